// Round 4
// baseline (692.901 us; speedup 1.0000x reference)
//
#include <hip/hip_runtime.h>
#include <hip/hip_bf16.h>

// GNN: node_proj + edge scatter_mean/proj -> concat -> GAT(512->4x64) -> ELU
//      -> GAT(256->4x64) -> ELU -> out_proj. ALL tensors float32 (per ref).
// R10: (1) GEMM: A register double-buffer — A(t+1) issued at top of k-step t,
//      consumed next step, so HBM latency hides under 24 MFMAs + 16 ds_reads
//      (R9 had prefetch distance 0; counters showed 3475 cy/k-step vs 215 cy
//      of MFMA). launch_bounds (256,3).
//      (2) agg: per-entry edge weights precomputed in edge_w_kernel (f32,
//      exact same math) + per-node denominators; removes the 16x-redundant
//      per-lane logit/exp work and the random a_src gather from the agg hot
//      loop. agg inner loop = col loads + broadcast w loads + FMAs only.

#define HEADS 4

typedef __attribute__((ext_vector_type(8))) short bf16x8;
typedef __attribute__((ext_vector_type(4))) float f32x4;
typedef __attribute__((ext_vector_type(4))) unsigned short u16x4;

__device__ __forceinline__ unsigned short f2b(float v) {
    __hip_bfloat16 b = __float2bfloat16(v);
    return __builtin_bit_cast(unsigned short, b);
}
__device__ __forceinline__ float b2f(unsigned short u) {
    __hip_bfloat16 b = __builtin_bit_cast(__hip_bfloat16, u);
    return __bfloat162float(b);
}
__device__ __forceinline__ void split_hilo(float v, unsigned short& h, unsigned short& l) {
    h = f2b(v);
    l = f2b(v - b2f(h));
}
__device__ __forceinline__ unsigned short f2h(float v) {
    _Float16 h = (_Float16)v;                 // v_cvt_f16_f32, RN
    return __builtin_bit_cast(unsigned short, h);
}
__device__ __forceinline__ float h2f(unsigned short u) {
    return (float)__builtin_bit_cast(_Float16, u);
}
// async global->LDS, 16B per lane; LDS dest is wave-uniform base + lane*16
__device__ __forceinline__ void gl2lds16(const unsigned short* g, unsigned short* l) {
    __builtin_amdgcn_global_load_lds(
        (const __attribute__((address_space(1))) unsigned int*)g,
        (__attribute__((address_space(3))) unsigned int*)l,
        16, 0, 0);
}

// ============================ CSR construction =============================

__global__ __launch_bounds__(256) void count_kernel(
    const int* __restrict__ dst, int* __restrict__ cnt, int E)
{
    int e = blockIdx.x * 256 + threadIdx.x;
    if (e < E) atomicAdd(&cnt[dst[e]], 1);
}

__global__ __launch_bounds__(256) void scan1_kernel(
    const int* __restrict__ cnt, int* __restrict__ chunk_sum, int N)
{
    __shared__ int sd[256];
    int t = threadIdx.x;
    int n = blockIdx.x * 256 + t;
    sd[t] = (n < N) ? (cnt[n] + 1) : 0;
    __syncthreads();
    for (int o = 128; o > 0; o >>= 1) {
        if (t < o) sd[t] += sd[t + o];
        __syncthreads();
    }
    if (t == 0) chunk_sum[blockIdx.x] = sd[0];
}

__global__ void scan2_kernel(const int* __restrict__ chunk_sum,
                             int* __restrict__ chunk_off, int nchunk)
{
    int acc = 0;
    for (int i = 0; i < nchunk; i++) {
        chunk_off[i] = acc;
        acc += chunk_sum[i];
    }
}

__global__ __launch_bounds__(256) void scan3_kernel(
    const int* __restrict__ cnt, const int* __restrict__ chunk_off,
    int* __restrict__ rowptr, int* __restrict__ fillptr,
    int* __restrict__ col, int* __restrict__ eid, int N)
{
    __shared__ int sd[256];
    int t = threadIdx.x;
    int n = blockIdx.x * 256 + t;
    int v = (n < N) ? (cnt[n] + 1) : 0;
    sd[t] = v;
    __syncthreads();
    for (int o = 1; o < 256; o <<= 1) {
        int x = (t >= o) ? sd[t - o] : 0;
        __syncthreads();
        sd[t] += x;
        __syncthreads();
    }
    if (n < N) {
        int incl = sd[t];
        int r = chunk_off[blockIdx.x] + incl - v;
        rowptr[n] = r;
        col[r] = n;        // self loop, first entry
        eid[r] = -1;
        fillptr[n] = r + 1;
        if (n == N - 1) rowptr[N] = chunk_off[blockIdx.x] + incl;
    }
}

__global__ __launch_bounds__(256) void fill_kernel(
    const int* __restrict__ src, const int* __restrict__ dst,
    int* __restrict__ fillptr, int* __restrict__ col, int* __restrict__ eid, int E)
{
    int e = blockIdx.x * 256 + threadIdx.x;
    if (e >= E) return;
    int d = dst[e];
    int p = atomicAdd(&fillptr[d], 1);
    col[p] = src[e];
    eid[p] = e;
}

// ====== edge_attr scatter-mean via CSR -> hi/lo bf16 [N x 32] (K-padded) ===
// 4 nodes per block: wave w handles node blockIdx*4+w.
__global__ __launch_bounds__(256) void nef_csr_kernel(
    const float* __restrict__ ea, const int* __restrict__ rowptr,
    const int* __restrict__ eid,
    unsigned short* __restrict__ nefH, unsigned short* __restrict__ nefL, int N)
{
    int n = blockIdx.x * 4 + (threadIdx.x >> 6);
    if (n >= N) return;
    int t = threadIdx.x & 63;
    int f = t & 15, g = t >> 4;
    int base = rowptr[n], end = rowptr[n + 1];
    int deg = end - base - 1;
    float acc = 0.0f;
    for (int j = base + 1 + g; j < end; j += 4) {
        int e = eid[j];
        acc += ea[(size_t)e * 16 + f];
    }
    acc += __shfl_down(acc, 32, 64);
    acc += __shfl_down(acc, 16, 64);
    if (t < 16) {
        float v = acc / fmaxf((float)deg, 1.0f);
        unsigned short h, l;
        split_hilo(v, h, l);
        nefH[(size_t)n * 32 + t] = h;
        nefL[(size_t)n * 32 + t] = l;
    } else if (t < 32) {
        nefH[(size_t)n * 32 + t] = 0;
        nefL[(size_t)n * 32 + t] = 0;
    }
}

// ============ convert f32 -> hi/lo bf16 (2 elems per thread) ===============
__global__ __launch_bounds__(256) void conv_hilo_kernel(
    const float* __restrict__ X,
    unsigned short* __restrict__ H, unsigned short* __restrict__ L, int total)
{
    int base = (blockIdx.x * 256 + threadIdx.x) * 2;
    if (base >= total) return;
    #pragma unroll
    for (int i = 0; i < 2; i++) {
        unsigned short h, l;
        split_hilo(X[base + i], h, l);
        H[base + i] = h;
        L[base + i] = l;
    }
}

// ============ pack weights [K x 256] -> B-fragment order, hi/lo ============
__global__ __launch_bounds__(256) void pack_w_kernel(
    const float* __restrict__ W, int K, int KP,
    unsigned short* __restrict__ Ph, unsigned short* __restrict__ Pl)
{
    int idx = blockIdx.x * 256 + threadIdx.x;
    if (idx >= KP * 256) return;
    int tile = idx >> 9, w = idx & 511, lane = w >> 3, j = w & 7;
    int nk = KP >> 5;
    int ctile = tile / nk, t = tile % nk;
    int k = t * 32 + ((lane >> 4) << 3) + j;
    int n = (ctile << 4) + (lane & 15);
    float v = (k < K) ? W[(size_t)k * 256 + n] : 0.0f;
    unsigned short h, l;
    split_hilo(v, h, l);
    Ph[idx] = h;
    Pl[idx] = l;
}

// ===================== MFMA bf16x3 GEMM ====================================
// C[N x 256] = A[N x KP] @ W[KP x 256] (+bias). Block: 128 rows x 128 cols
// (grid.y=2), 4 waves (wave = 32 rows = 2 fragments), 8 col-tiles.
// B panel double-buffered in LDS via global_load_lds; A register
// double-buffered (A(t+1) issued before MFMAs of t -> one k-step of latency
// cover before the barrier drain). One barrier per k-step. OMODE: 0 = f32,
// 1 = hi/lo bf16, 2 = fp16. FUSE_ATT: per-row per-head attention dots from
// accumulators; head 2y+hl fully inside col-half y -> direct store.
template <int KSTEPS, int OMODE, bool FUSE_ATT>
__global__ __launch_bounds__(256, 3) void mfma_gemm_kernel(
    const unsigned short* __restrict__ Ah, const unsigned short* __restrict__ Al,
    int lda,
    const unsigned short* __restrict__ Ph, const unsigned short* __restrict__ Pl,
    const float* __restrict__ bias,
    float* __restrict__ Cf,
    unsigned short* __restrict__ Ch, unsigned short* __restrict__ Cl,
    int ldc, int col_off, int Nrows,
    const float* __restrict__ att_src, const float* __restrict__ att_dst,
    float* __restrict__ a_srcO, float* __restrict__ a_dstO)
{
    __shared__ unsigned short ldsB[2][2][8][512];   // [buf][hi/lo][ctile][elem]
    int tid = threadIdx.x;
    int wave = tid >> 6, lane = tid & 63;
    int quad = lane >> 4, m16 = lane & 15;
    int rowblk = blockIdx.x, colhalf = blockIdx.y;
    int ctile0 = colhalf * 8;

    int row0 = rowblk * 128 + wave * 32 + m16;
    int row1 = row0 + 16;
    bool ok0 = row0 < Nrows, ok1 = row1 < Nrows;
    const unsigned short* arh0 = Ah + (size_t)row0 * lda;
    const unsigned short* arl0 = Al + (size_t)row0 * lda;
    const unsigned short* arh1 = Ah + (size_t)row1 * lda;
    const unsigned short* arl1 = Al + (size_t)row1 * lda;

    // wave w stages ctiles {2w, 2w+1} (hi+lo) of k-step t into buf
    auto stage = [&](int t, int buf) {
        #pragma unroll
        for (int q = 0; q < 2; q++) {
            int c = wave * 2 + q;
            size_t gb = ((size_t)((ctile0 + c) * KSTEPS + t)) * 512 + lane * 8;
            gl2lds16(Ph + gb, &ldsB[buf][0][c][0]);
            gl2lds16(Pl + gb, &ldsB[buf][1][c][0]);
        }
    };
    auto loadA = [&](int t, bf16x8& h0, bf16x8& l0, bf16x8& h1, bf16x8& l1) {
        int k = t * 32 + quad * 8;
        h0 = l0 = h1 = l1 = (bf16x8){};
        if (ok0) {
            h0 = *(const bf16x8*)(arh0 + k);
            l0 = *(const bf16x8*)(arl0 + k);
        }
        if (ok1) {
            h1 = *(const bf16x8*)(arh1 + k);
            l1 = *(const bf16x8*)(arl1 + k);
        }
    };

    f32x4 acc[2][8] = {};
    bf16x8 cah0, cal0, cah1, cal1, nah0, nal0, nah1, nal1;
    loadA(0, cah0, cal0, cah1, cal1);
    stage(0, 0);
    __syncthreads();

    #pragma unroll
    for (int t = 0; t < KSTEPS; t++) {
        const int buf = t & 1;
        if (t + 1 < KSTEPS) {
            stage(t + 1, buf ^ 1);
            loadA(t + 1, nah0, nal0, nah1, nal1);
        }
        #pragma unroll
        for (int c = 0; c < 8; c++) {
            bf16x8 b_h = *(const bf16x8*)&ldsB[buf][0][c][lane * 8];
            bf16x8 b_l = *(const bf16x8*)&ldsB[buf][1][c][lane * 8];
            acc[0][c] = __builtin_amdgcn_mfma_f32_16x16x32_bf16(cah0, b_h, acc[0][c], 0, 0, 0);
            acc[0][c] = __builtin_amdgcn_mfma_f32_16x16x32_bf16(cal0, b_h, acc[0][c], 0, 0, 0);
            acc[0][c] = __builtin_amdgcn_mfma_f32_16x16x32_bf16(cah0, b_l, acc[0][c], 0, 0, 0);
            acc[1][c] = __builtin_amdgcn_mfma_f32_16x16x32_bf16(cah1, b_h, acc[1][c], 0, 0, 0);
            acc[1][c] = __builtin_amdgcn_mfma_f32_16x16x32_bf16(cal1, b_h, acc[1][c], 0, 0, 0);
            acc[1][c] = __builtin_amdgcn_mfma_f32_16x16x32_bf16(cah1, b_l, acc[1][c], 0, 0, 0);
        }
        if (t + 1 < KSTEPS) {
            __syncthreads();
            cah0 = nah0; cal0 = nal0; cah1 = nah1; cal1 = nal1;
        }
    }

    // epilogue: D[row = quad*4 + r][col = m16] within each 16x16 tile
    #pragma unroll
    for (int f = 0; f < 2; f++) {
        #pragma unroll
        for (int c = 0; c < 8; c++) {
            int ocol = (ctile0 + c) * 16 + m16;
            float bv = bias ? bias[ocol] : 0.0f;
            #pragma unroll
            for (int r = 0; r < 4; r++) {
                int orow = rowblk * 128 + wave * 32 + f * 16 + quad * 4 + r;
                if (orow >= Nrows) continue;
                float v = acc[f][c][r] + bv;
                size_t oidx = (size_t)orow * ldc + col_off + ocol;
                if (OMODE == 1) {
                    unsigned short h, l;
                    split_hilo(v, h, l);
                    Ch[oidx] = h;
                    Cl[oidx] = l;
                } else if (OMODE == 2) {
                    Ch[oidx] = f2h(v);
                } else {
                    Cf[oidx] = v;
                }
            }
        }
    }

    if (FUSE_ATT) {
        #pragma unroll
        for (int f = 0; f < 2; f++) {
            float ps[4][2] = {}, pd[4][2] = {};
            #pragma unroll
            for (int c = 0; c < 8; c++) {
                int ocol = (ctile0 + c) * 16 + m16;
                float asv = att_src[ocol];
                float adv = att_dst[ocol];
                int hl = c >> 2;
                #pragma unroll
                for (int r = 0; r < 4; r++) {
                    ps[r][hl] += acc[f][c][r] * asv;
                    pd[r][hl] += acc[f][c][r] * adv;
                }
            }
            #pragma unroll
            for (int r = 0; r < 4; r++) {
                #pragma unroll
                for (int hl = 0; hl < 2; hl++) {
                    float s = ps[r][hl], d = pd[r][hl];
                    #pragma unroll
                    for (int o = 8; o > 0; o >>= 1) {
                        s += __shfl_down(s, o, 64);
                        d += __shfl_down(d, o, 64);
                    }
                    if (m16 == 0) {
                        int orow = rowblk * 128 + wave * 32 + f * 16 + quad * 4 + r;
                        if (orow < Nrows) {
                            int gh = colhalf * 2 + hl;
                            a_srcO[orow * 4 + gh] = s;
                            a_dstO[orow * 4 + gh] = d;
                        }
                    }
                }
            }
        }
    }
}

// ===== edge weights: w[j][h] = exp(lrelu(a_src[col[j]][h] + a_dst[n][h])) ==
// 4 nodes/block, wave per node, lane per CSR entry (stride 64). Also
// wave-reduces the per-head denominator (sum of w over the node's entries).
// f32 storage -> numerically identical to computing in the agg loop.
__global__ __launch_bounds__(256) void edge_w_kernel(
    const int* __restrict__ rowptr, const int* __restrict__ col,
    const float* __restrict__ a_src, const float* __restrict__ a_dst,
    float* __restrict__ wq, float* __restrict__ den, int N)
{
    int n = blockIdx.x * 4 + (threadIdx.x >> 6);
    if (n >= N) return;
    int lane = threadIdx.x & 63;
    int base = rowptr[n], end = rowptr[n + 1];
    float4 ad = *(const float4*)&a_dst[n * 4];
    float4 ds = {0.0f, 0.0f, 0.0f, 0.0f};
    for (int j = base + lane; j < end; j += 64) {
        int s = col[j];
        float4 as4 = *(const float4*)&a_src[s * 4];
        float l0 = as4.x + ad.x, l1 = as4.y + ad.y;
        float l2 = as4.z + ad.z, l3 = as4.w + ad.w;
        l0 = fmaxf(l0, 0.2f * l0);
        l1 = fmaxf(l1, 0.2f * l1);
        l2 = fmaxf(l2, 0.2f * l2);
        l3 = fmaxf(l3, 0.2f * l3);
        float4 wv = {__expf(l0), __expf(l1), __expf(l2), __expf(l3)};
        *(float4*)&wq[(size_t)j * 4] = wv;
        ds.x += wv.x; ds.y += wv.y; ds.z += wv.z; ds.w += wv.w;
    }
    #pragma unroll
    for (int o = 32; o > 0; o >>= 1) {
        ds.x += __shfl_down(ds.x, o, 64);
        ds.y += __shfl_down(ds.y, o, 64);
        ds.z += __shfl_down(ds.z, o, 64);
        ds.w += __shfl_down(ds.w, o, 64);
    }
    if (lane == 0) *(float4*)&den[n * 4] = ds;
}

// ===== CSR aggregation: wave-per-node weighted sum + bias + ELU ============
// 4 nodes per 256-thread block; wave w owns node blockIdx*4+w. Each lane
// covers 4 consecutive cols (64 lanes x 4 halves = full 256-col fp16 row).
// Weights precomputed (edge_w_kernel): inner loop is col loads + broadcast
// w loads + FMAs only. Masked unroll-4; no LDS, no __syncthreads.
__global__ __launch_bounds__(256) void gat_agg_csr_kernel(
    const unsigned short* __restrict__ xh,      // fp16 [N x 256]
    const int* __restrict__ rowptr, const int* __restrict__ col,
    const float* __restrict__ wq, const float* __restrict__ den,
    const float* __restrict__ bias,
    unsigned short* __restrict__ outH, unsigned short* __restrict__ outL, int N)
{
    int t = threadIdx.x;
    int n = blockIdx.x * 4 + (t >> 6);
    if (n >= N) return;
    int c = t & 63;
    int h = c >> 4;
    int base = rowptr[n], end = rowptr[n + 1];
    int e1 = end - 1;                      // >= base (self loop guaranteed)
    float inv = 1.0f / den[n * 4 + h];
    const unsigned short* xcol = xh + (c << 2);

    float4 acc = {0.0f, 0.0f, 0.0f, 0.0f};
    for (int j = base; j < end; j += 4) {
        int j1 = j + 1 < e1 ? j + 1 : e1;
        int j2 = j + 2 < e1 ? j + 2 : e1;
        int j3 = j + 3 < e1 ? j + 3 : e1;
        int s0 = col[j], s1 = col[j1], s2 = col[j2], s3 = col[j3];
        float w0 = wq[(size_t)j * 4 + h];
        float w1 = (j + 1 < end) ? wq[(size_t)j1 * 4 + h] : 0.0f;
        float w2 = (j + 2 < end) ? wq[(size_t)j2 * 4 + h] : 0.0f;
        float w3 = (j + 3 < end) ? wq[(size_t)j3 * 4 + h] : 0.0f;
        u16x4 x0 = *(const u16x4*)(xcol + (size_t)s0 * 256);
        u16x4 x1 = *(const u16x4*)(xcol + (size_t)s1 * 256);
        u16x4 x2 = *(const u16x4*)(xcol + (size_t)s2 * 256);
        u16x4 x3 = *(const u16x4*)(xcol + (size_t)s3 * 256);
        acc.x += w0 * h2f(x0[0]) + w1 * h2f(x1[0]) + w2 * h2f(x2[0]) + w3 * h2f(x3[0]);
        acc.y += w0 * h2f(x0[1]) + w1 * h2f(x1[1]) + w2 * h2f(x2[1]) + w3 * h2f(x3[1]);
        acc.z += w0 * h2f(x0[2]) + w1 * h2f(x1[2]) + w2 * h2f(x2[2]) + w3 * h2f(x3[2]);
        acc.w += w0 * h2f(x0[3]) + w1 * h2f(x1[3]) + w2 * h2f(x2[3]) + w3 * h2f(x3[3]);
    }

    float4 bv = *(const float4*)(bias + (c << 2));
    float o0 = acc.x * inv + bv.x;
    float o1 = acc.y * inv + bv.y;
    float o2 = acc.z * inv + bv.z;
    float o3 = acc.w * inv + bv.w;
    o0 = (o0 > 0.0f) ? o0 : (__expf(o0) - 1.0f);
    o1 = (o1 > 0.0f) ? o1 : (__expf(o1) - 1.0f);
    o2 = (o2 > 0.0f) ? o2 : (__expf(o2) - 1.0f);
    o3 = (o3 > 0.0f) ? o3 : (__expf(o3) - 1.0f);
    u16x4 H, L;
    split_hilo(o0, ((unsigned short*)&H)[0], ((unsigned short*)&L)[0]);
    split_hilo(o1, ((unsigned short*)&H)[1], ((unsigned short*)&L)[1]);
    split_hilo(o2, ((unsigned short*)&H)[2], ((unsigned short*)&L)[2]);
    split_hilo(o3, ((unsigned short*)&H)[3], ((unsigned short*)&L)[3]);
    *(u16x4*)(&outH[(size_t)n * 256 + (c << 2)]) = H;
    *(u16x4*)(&outL[(size_t)n * 256 + (c << 2)]) = L;
}

// ===========================================================================

extern "C" void kernel_launch(void* const* d_in, const int* in_sizes, int n_in,
                              void* d_out, int out_size, void* d_ws, size_t ws_size,
                              hipStream_t stream)
{
    const float* node_feats = (const float*)d_in[0];
    const float* edge_attr  = (const float*)d_in[1];
    const float* Wnp = (const float*)d_in[2];
    const float* bnp = (const float*)d_in[3];
    const float* Wep = (const float*)d_in[4];
    const float* bep = (const float*)d_in[5];
    const float* Wg1 = (const float*)d_in[6];
    const float* as1 = (const float*)d_in[7];
    const float* ad1 = (const float*)d_in[8];
    const float* bg1 = (const float*)d_in[9];
    const float* Wg2 = (const float*)d_in[10];
    const float* as2 = (const float*)d_in[11];
    const float* ad2 = (const float*)d_in[12];
    const float* bg2 = (const float*)d_in[13];
    const float* Wo  = (const float*)d_in[14];
    const float* bo  = (const float*)d_in[15];
    const int*   ei  = (const int*)d_in[16];

    const int N = in_sizes[0] / 128;   // 50000
    const int E = in_sizes[16] / 2;    // 800000
    const int* src = ei;
    const int* dst = ei + E;
    const int nchunk = (N + 255) / 256;
    const int EN = E + N;

    typedef unsigned short u16;

    // ---- workspace layout (256B-aligned regions) ----
    char* base = (char*)d_ws;
    size_t off = 0;
    auto alloc = [&](size_t bytes) -> char* {
        char* p = base + off;
        off += (bytes + 255) & ~(size_t)255;
        return p;
    };
    // xh region sized for the nf/nef alias layout (N*640 B); fp16 xh uses N*512 B
    char* xreg = alloc((size_t)N * 256 * 4);
    u16* xhh  = (u16*)xreg;                                // fp16 xh [N x 256]
    u16* x2H  = (u16*)alloc((size_t)N * 512 * 2);          // hosts x3H/x3L after GEMM3
    u16* x2L  = (u16*)alloc((size_t)N * 512 * 2);          // hosts x4H/x4L after GEMM3
    float* a_src = (float*)alloc((size_t)N * 4 * 4);
    float* a_dst = (float*)alloc((size_t)N * 4 * 4);
    float* wq    = (float*)alloc((size_t)EN * 4 * 4);      // per-entry weights [EN x 4]
    float* den   = (float*)alloc((size_t)N * 4 * 4);       // per-node denominators
    u16* PnpH = (u16*)alloc(128 * 256 * 2);
    u16* PnpL = (u16*)alloc(128 * 256 * 2);
    u16* PepH = (u16*)alloc(32 * 256 * 2);
    u16* PepL = (u16*)alloc(32 * 256 * 2);
    u16* Pg1H = (u16*)alloc(512 * 256 * 2);
    u16* Pg1L = (u16*)alloc(512 * 256 * 2);
    u16* Pg2H = (u16*)alloc(256 * 256 * 2);
    u16* Pg2L = (u16*)alloc(256 * 256 * 2);
    u16* PoH  = (u16*)alloc(256 * 256 * 2);
    u16* PoL  = (u16*)alloc(256 * 256 * 2);
    int* cnt       = (int*)alloc((size_t)N * 4);
    int* rowptr    = (int*)alloc((size_t)(N + 1) * 4);
    int* fillptr   = (int*)alloc((size_t)N * 4);
    int* chunk_sum = (int*)alloc((size_t)nchunk * 4);
    int* chunk_off = (int*)alloc((size_t)nchunk * 4);
    int* colv      = (int*)alloc((size_t)EN * 4);
    int* eid       = (int*)alloc((size_t)EN * 4);

    // aliases inside xh region (dead before GEMM writes xhh)
    u16* nfH  = (u16*)xreg;
    u16* nfL  = nfH + (size_t)N * 128;
    u16* nefH = nfL + (size_t)N * 128;
    u16* nefL = nefH + (size_t)N * 32;
    // aliases inside x2 regions (x2 dead after GEMM3)
    u16* x3H = x2H;
    u16* x3L = x2H + (size_t)N * 256;
    u16* x4H = x2L;
    u16* x4L = x2L + (size_t)N * 256;

    float* out = (float*)d_out;
    dim3 ggrid((N + 127) / 128, 2);

    // ---- CSR build ----
    hipMemsetAsync(cnt, 0, (size_t)N * sizeof(int), stream);
    count_kernel<<<(E + 255) / 256, 256, 0, stream>>>(dst, cnt, E);
    scan1_kernel<<<nchunk, 256, 0, stream>>>(cnt, chunk_sum, N);
    scan2_kernel<<<1, 1, 0, stream>>>(chunk_sum, chunk_off, nchunk);
    scan3_kernel<<<nchunk, 256, 0, stream>>>(cnt, chunk_off, rowptr, fillptr, colv, eid, N);
    fill_kernel<<<(E + 255) / 256, 256, 0, stream>>>(src, dst, fillptr, colv, eid, E);

    // ---- input conversions + weight packing ----
    nef_csr_kernel<<<(N + 3) / 4, 256, 0, stream>>>(edge_attr, rowptr, eid, nefH, nefL, N);
    conv_hilo_kernel<<<((N * 128) / 2 + 255) / 256, 256, 0, stream>>>(
        node_feats, nfH, nfL, N * 128);
    pack_w_kernel<<<(128 * 256 + 255) / 256, 256, 0, stream>>>(Wnp, 128, 128, PnpH, PnpL);
    pack_w_kernel<<<(32 * 256 + 255) / 256, 256, 0, stream>>>(Wep, 16, 32, PepH, PepL);
    pack_w_kernel<<<(512 * 256 + 255) / 256, 256, 0, stream>>>(Wg1, 512, 512, Pg1H, Pg1L);
    pack_w_kernel<<<(256 * 256 + 255) / 256, 256, 0, stream>>>(Wg2, 256, 256, Pg2H, Pg2L);
    pack_w_kernel<<<(256 * 256 + 255) / 256, 256, 0, stream>>>(Wo, 256, 256, PoH, PoL);

    // ---- x2 = [ nf@Wnp + bnp | nef@Wep + bep ] -> x2H/x2L [N x 512] ----
    mfma_gemm_kernel<4, 1, false><<<ggrid, 256, 0, stream>>>(
        nfH, nfL, 128, PnpH, PnpL, bnp, nullptr, x2H, x2L, 512, 0, N,
        nullptr, nullptr, nullptr, nullptr);
    mfma_gemm_kernel<1, 1, false><<<ggrid, 256, 0, stream>>>(
        nefH, nefL, 32, PepH, PepL, bep, nullptr, x2H, x2L, 512, 256, N,
        nullptr, nullptr, nullptr, nullptr);

    // ---- GAT layer 1: GEMM (+fused att dots, fp16 xh out) -> w -> agg ----
    mfma_gemm_kernel<16, 2, true><<<ggrid, 256, 0, stream>>>(
        x2H, x2L, 512, Pg1H, Pg1L, nullptr, nullptr, xhh, nullptr, 256, 0, N,
        as1, ad1, a_src, a_dst);
    edge_w_kernel<<<(N + 3) / 4, 256, 0, stream>>>(
        rowptr, colv, a_src, a_dst, wq, den, N);
    gat_agg_csr_kernel<<<(N + 3) / 4, 256, 0, stream>>>(
        xhh, rowptr, colv, wq, den, bg1, x3H, x3L, N);

    // ---- GAT layer 2 ----
    mfma_gemm_kernel<8, 2, true><<<ggrid, 256, 0, stream>>>(
        x3H, x3L, 256, Pg2H, Pg2L, nullptr, nullptr, xhh, nullptr, 256, 0, N,
        as2, ad2, a_src, a_dst);
    edge_w_kernel<<<(N + 3) / 4, 256, 0, stream>>>(
        rowptr, colv, a_src, a_dst, wq, den, N);
    gat_agg_csr_kernel<<<(N + 3) / 4, 256, 0, stream>>>(
        xhh, rowptr, colv, wq, den, bg2, x4H, x4L, N);

    // ---- out = x4 @ Wo + bo -> d_out (f32) ----
    mfma_gemm_kernel<8, 0, false><<<ggrid, 256, 0, stream>>>(
        x4H, x4L, 256, PoH, PoL, bo, out, nullptr, nullptr, 256, 0, N,
        nullptr, nullptr, nullptr, nullptr);
}

// Round 5
// 584.104 us; speedup vs baseline: 1.1863x; 1.1863x over previous
//
#include <hip/hip_runtime.h>
#include <hip/hip_bf16.h>

// GNN: node_proj + edge scatter_mean/proj -> concat -> GAT(512->4x64) -> ELU
//      -> GAT(256->4x64) -> ELU -> out_proj. ALL tensors float32 (per ref).
// R11: (1) ALGEBRAIC: front is linear -> precompose on device:
//      xh1 = nf @ (Wnp@Wg1_top) + nef_raw @ (Wep@Wg1_bot) + c1.
//      GAT1 GEMM K: 512 -> 144 (pad 160); np/ep GEMMs + x2 buffer deleted.
//      (2) GEMM: revert R10 A-prefetch (syncthreads' vmcnt(0) drains the
//      prefetch in the same k-step -> pure cost, 70.8->80.2 regression).
//      (3) GEMM blocks 128->64 rows: grid 782->1564 (6.1/CU, LDS caps 5
//      resident) to fix the 20% occupancy latency exposure.

#define HEADS 4

typedef __attribute__((ext_vector_type(8))) short bf16x8;
typedef __attribute__((ext_vector_type(4))) float f32x4;
typedef __attribute__((ext_vector_type(4))) unsigned short u16x4;

__device__ __forceinline__ unsigned short f2b(float v) {
    __hip_bfloat16 b = __float2bfloat16(v);
    return __builtin_bit_cast(unsigned short, b);
}
__device__ __forceinline__ float b2f(unsigned short u) {
    __hip_bfloat16 b = __builtin_bit_cast(__hip_bfloat16, u);
    return __bfloat162float(b);
}
__device__ __forceinline__ void split_hilo(float v, unsigned short& h, unsigned short& l) {
    h = f2b(v);
    l = f2b(v - b2f(h));
}
__device__ __forceinline__ unsigned short f2h(float v) {
    _Float16 h = (_Float16)v;                 // v_cvt_f16_f32, RN
    return __builtin_bit_cast(unsigned short, h);
}
__device__ __forceinline__ float h2f(unsigned short u) {
    return (float)__builtin_bit_cast(_Float16, u);
}
// async global->LDS, 16B per lane; LDS dest is wave-uniform base + lane*16
__device__ __forceinline__ void gl2lds16(const unsigned short* g, unsigned short* l) {
    __builtin_amdgcn_global_load_lds(
        (const __attribute__((address_space(1))) unsigned int*)g,
        (__attribute__((address_space(3))) unsigned int*)l,
        16, 0, 0);
}

// ============================ CSR construction =============================

__global__ __launch_bounds__(256) void count_kernel(
    const int* __restrict__ dst, int* __restrict__ cnt, int E)
{
    int e = blockIdx.x * 256 + threadIdx.x;
    if (e < E) atomicAdd(&cnt[dst[e]], 1);
}

__global__ __launch_bounds__(256) void scan1_kernel(
    const int* __restrict__ cnt, int* __restrict__ chunk_sum, int N)
{
    __shared__ int sd[256];
    int t = threadIdx.x;
    int n = blockIdx.x * 256 + t;
    sd[t] = (n < N) ? (cnt[n] + 1) : 0;
    __syncthreads();
    for (int o = 128; o > 0; o >>= 1) {
        if (t < o) sd[t] += sd[t + o];
        __syncthreads();
    }
    if (t == 0) chunk_sum[blockIdx.x] = sd[0];
}

__global__ void scan2_kernel(const int* __restrict__ chunk_sum,
                             int* __restrict__ chunk_off, int nchunk)
{
    int acc = 0;
    for (int i = 0; i < nchunk; i++) {
        chunk_off[i] = acc;
        acc += chunk_sum[i];
    }
}

__global__ __launch_bounds__(256) void scan3_kernel(
    const int* __restrict__ cnt, const int* __restrict__ chunk_off,
    int* __restrict__ rowptr, int* __restrict__ fillptr,
    int* __restrict__ col, int* __restrict__ eid, int N)
{
    __shared__ int sd[256];
    int t = threadIdx.x;
    int n = blockIdx.x * 256 + t;
    int v = (n < N) ? (cnt[n] + 1) : 0;
    sd[t] = v;
    __syncthreads();
    for (int o = 1; o < 256; o <<= 1) {
        int x = (t >= o) ? sd[t - o] : 0;
        __syncthreads();
        sd[t] += x;
        __syncthreads();
    }
    if (n < N) {
        int incl = sd[t];
        int r = chunk_off[blockIdx.x] + incl - v;
        rowptr[n] = r;
        col[r] = n;        // self loop, first entry
        eid[r] = -1;
        fillptr[n] = r + 1;
        if (n == N - 1) rowptr[N] = chunk_off[blockIdx.x] + incl;
    }
}

__global__ __launch_bounds__(256) void fill_kernel(
    const int* __restrict__ src, const int* __restrict__ dst,
    int* __restrict__ fillptr, int* __restrict__ col, int* __restrict__ eid, int E)
{
    int e = blockIdx.x * 256 + threadIdx.x;
    if (e >= E) return;
    int d = dst[e];
    int p = atomicAdd(&fillptr[d], 1);
    col[p] = src[e];
    eid[p] = e;
}

// ====== edge_attr scatter-mean via CSR -> hi/lo bf16 into Acat cols 128+ ===
// Acat row layout [N x 160]: cols 0..127 nf, 128..143 nef_raw, 144..159 zero.
// 4 nodes per block: wave w handles node blockIdx*4+w.
__global__ __launch_bounds__(256) void nef_csr_kernel(
    const float* __restrict__ ea, const int* __restrict__ rowptr,
    const int* __restrict__ eid,
    unsigned short* __restrict__ AH, unsigned short* __restrict__ AL, int N)
{
    int n = blockIdx.x * 4 + (threadIdx.x >> 6);
    if (n >= N) return;
    int t = threadIdx.x & 63;
    int f = t & 15, g = t >> 4;
    int base = rowptr[n], end = rowptr[n + 1];
    int deg = end - base - 1;
    float acc = 0.0f;
    for (int j = base + 1 + g; j < end; j += 4) {
        int e = eid[j];
        acc += ea[(size_t)e * 16 + f];
    }
    acc += __shfl_down(acc, 32, 64);
    acc += __shfl_down(acc, 16, 64);
    if (t < 16) {
        float v = acc / fmaxf((float)deg, 1.0f);
        unsigned short h, l;
        split_hilo(v, h, l);
        AH[(size_t)n * 160 + 128 + t] = h;
        AL[(size_t)n * 160 + 128 + t] = l;
    } else if (t < 32) {
        AH[(size_t)n * 160 + 128 + t] = 0;
        AL[(size_t)n * 160 + 128 + t] = 0;
    }
}

// ====== convert node_feats f32 [N x 128] -> hi/lo bf16 into Acat cols 0-127
__global__ __launch_bounds__(256) void conv_hilo_strided_kernel(
    const float* __restrict__ X,
    unsigned short* __restrict__ H, unsigned short* __restrict__ L, int total)
{
    int base = (blockIdx.x * 256 + threadIdx.x) * 2;
    if (base >= total) return;
    #pragma unroll
    for (int i = 0; i < 2; i++) {
        int e = base + i;
        int row = e >> 7, c = e & 127;
        unsigned short h, l;
        split_hilo(X[e], h, l);
        H[(size_t)row * 160 + c] = h;
        L[(size_t)row * 160 + c] = l;
    }
}

// ====== compose front-end weights (f32, exact):
// Wc rows 0..127 = Wnp @ Wg1[0:256,:], rows 128..143 = Wep @ Wg1[256:512,:],
// c1[j] = bnp @ Wg1[0:256,j] + bep @ Wg1[256:512,j].
__global__ __launch_bounds__(256) void compose_w1_kernel(
    const float* __restrict__ Wnp, const float* __restrict__ Wep,
    const float* __restrict__ bnp, const float* __restrict__ bep,
    const float* __restrict__ Wg1,
    float* __restrict__ Wc, float* __restrict__ c1)
{
    int idx = blockIdx.x * 256 + threadIdx.x;
    if (idx >= 145 * 256) return;
    int i = idx >> 8, j = idx & 255;
    float s = 0.0f;
    if (i < 128) {
        for (int k = 0; k < 256; k++) s += Wnp[i * 256 + k] * Wg1[(size_t)k * 256 + j];
        Wc[i * 256 + j] = s;
    } else if (i < 144) {
        int ii = i - 128;
        for (int k = 0; k < 256; k++) s += Wep[ii * 256 + k] * Wg1[(size_t)(256 + k) * 256 + j];
        Wc[i * 256 + j] = s;
    } else {
        for (int k = 0; k < 256; k++)
            s += bnp[k] * Wg1[(size_t)k * 256 + j] + bep[k] * Wg1[(size_t)(256 + k) * 256 + j];
        c1[j] = s;
    }
}

// ============ pack weights [K x 256] -> B-fragment order, hi/lo ============
__global__ __launch_bounds__(256) void pack_w_kernel(
    const float* __restrict__ W, int K, int KP,
    unsigned short* __restrict__ Ph, unsigned short* __restrict__ Pl)
{
    int idx = blockIdx.x * 256 + threadIdx.x;
    if (idx >= KP * 256) return;
    int tile = idx >> 9, w = idx & 511, lane = w >> 3, j = w & 7;
    int nk = KP >> 5;
    int ctile = tile / nk, t = tile % nk;
    int k = t * 32 + ((lane >> 4) << 3) + j;
    int n = (ctile << 4) + (lane & 15);
    float v = (k < K) ? W[(size_t)k * 256 + n] : 0.0f;
    unsigned short h, l;
    split_hilo(v, h, l);
    Ph[idx] = h;
    Pl[idx] = l;
}

// ===================== MFMA bf16x3 GEMM ====================================
// C[N x 256] = A[N x KP] @ W[KP x 256] (+bias). Block: 64 rows x 128 cols
// (grid.y=2), 4 waves (wave = 16 rows), 8 col-tiles. B panel double-buffered
// in LDS via global_load_lds (shared by all waves), one barrier per k-step,
// A loaded in-step (R10's prefetch regressed: barrier vmcnt(0) drains it
// same-step anyway). LDS 32KB -> 5 blocks/CU; launch_bounds(256,5).
// OMODE: 0 = f32, 1 = hi/lo bf16, 2 = fp16. FUSE_ATT: per-row per-head
// attention dots from (acc+bias); head 2y+hl fully inside col-half y.
template <int KSTEPS, int OMODE, bool FUSE_ATT>
__global__ __launch_bounds__(256, 5) void mfma_gemm_kernel(
    const unsigned short* __restrict__ Ah, const unsigned short* __restrict__ Al,
    int lda,
    const unsigned short* __restrict__ Ph, const unsigned short* __restrict__ Pl,
    const float* __restrict__ bias,
    float* __restrict__ Cf,
    unsigned short* __restrict__ Ch, unsigned short* __restrict__ Cl,
    int ldc, int col_off, int Nrows,
    const float* __restrict__ att_src, const float* __restrict__ att_dst,
    float* __restrict__ a_srcO, float* __restrict__ a_dstO)
{
    __shared__ unsigned short ldsB[2][2][8][512];   // [buf][hi/lo][ctile][elem]
    int tid = threadIdx.x;
    int wave = tid >> 6, lane = tid & 63;
    int quad = lane >> 4, m16 = lane & 15;
    int rowblk = blockIdx.x, colhalf = blockIdx.y;
    int ctile0 = colhalf * 8;

    int row = rowblk * 64 + wave * 16 + m16;
    bool rowok = row < Nrows;
    const unsigned short* arh = Ah + (size_t)row * lda;
    const unsigned short* arl = Al + (size_t)row * lda;

    // wave w stages ctiles {2w, 2w+1} (hi+lo) of k-step t into buf
    auto stage = [&](int t, int buf) {
        #pragma unroll
        for (int q = 0; q < 2; q++) {
            int c = wave * 2 + q;
            size_t gb = ((size_t)((ctile0 + c) * KSTEPS + t)) * 512 + lane * 8;
            gl2lds16(Ph + gb, &ldsB[buf][0][c][0]);
            gl2lds16(Pl + gb, &ldsB[buf][1][c][0]);
        }
    };

    f32x4 acc[8] = {};
    stage(0, 0);
    __syncthreads();

    for (int t = 0; t < KSTEPS; t++) {
        const int buf = t & 1;
        if (t + 1 < KSTEPS) stage(t + 1, buf ^ 1);
        int k = t * 32 + quad * 8;
        bf16x8 a_h = {}, a_l = {};
        if (rowok) {
            a_h = *(const bf16x8*)(arh + k);
            a_l = *(const bf16x8*)(arl + k);
        }
        #pragma unroll
        for (int c = 0; c < 8; c++) {
            bf16x8 b_h = *(const bf16x8*)&ldsB[buf][0][c][lane * 8];
            bf16x8 b_l = *(const bf16x8*)&ldsB[buf][1][c][lane * 8];
            acc[c] = __builtin_amdgcn_mfma_f32_16x16x32_bf16(a_h, b_h, acc[c], 0, 0, 0);
            acc[c] = __builtin_amdgcn_mfma_f32_16x16x32_bf16(a_l, b_h, acc[c], 0, 0, 0);
            acc[c] = __builtin_amdgcn_mfma_f32_16x16x32_bf16(a_h, b_l, acc[c], 0, 0, 0);
        }
        if (t + 1 < KSTEPS) __syncthreads();
    }

    // epilogue: D[row = quad*4 + r][col = m16] within each 16x16 tile
    #pragma unroll
    for (int c = 0; c < 8; c++) {
        int ocol = (ctile0 + c) * 16 + m16;
        float bv = bias ? bias[ocol] : 0.0f;
        #pragma unroll
        for (int r = 0; r < 4; r++) {
            int orow = rowblk * 64 + wave * 16 + quad * 4 + r;
            if (orow >= Nrows) continue;
            float v = acc[c][r] + bv;
            size_t oidx = (size_t)orow * ldc + col_off + ocol;
            if (OMODE == 1) {
                unsigned short h, l;
                split_hilo(v, h, l);
                Ch[oidx] = h;
                Cl[oidx] = l;
            } else if (OMODE == 2) {
                Ch[oidx] = f2h(v);
            } else {
                Cf[oidx] = v;
            }
        }
    }

    if (FUSE_ATT) {
        // per-row (r), per-local-head (hl=c>>2) attention dots of (acc+bias)
        float ps[4][2] = {}, pd[4][2] = {};
        #pragma unroll
        for (int c = 0; c < 8; c++) {
            int ocol = (ctile0 + c) * 16 + m16;
            float bv = bias ? bias[ocol] : 0.0f;
            float asv = att_src[ocol];
            float adv = att_dst[ocol];
            int hl = c >> 2;
            #pragma unroll
            for (int r = 0; r < 4; r++) {
                float v = acc[c][r] + bv;
                ps[r][hl] += v * asv;
                pd[r][hl] += v * adv;
            }
        }
        #pragma unroll
        for (int r = 0; r < 4; r++) {
            #pragma unroll
            for (int hl = 0; hl < 2; hl++) {
                float s = ps[r][hl], d = pd[r][hl];
                #pragma unroll
                for (int o = 8; o > 0; o >>= 1) {
                    s += __shfl_down(s, o, 64);
                    d += __shfl_down(d, o, 64);
                }
                if (m16 == 0) {
                    int orow = rowblk * 64 + wave * 16 + quad * 4 + r;
                    if (orow < Nrows) {
                        int gh = colhalf * 2 + hl;
                        a_srcO[orow * 4 + gh] = s;
                        a_dstO[orow * 4 + gh] = d;
                    }
                }
            }
        }
    }
}

// ===== edge weights: w[j][h] = exp(lrelu(a_src[col[j]][h] + a_dst[n][h])) ==
// 4 nodes/block, wave per node, lane per CSR entry (stride 64). Also
// wave-reduces the per-head denominator.
__global__ __launch_bounds__(256) void edge_w_kernel(
    const int* __restrict__ rowptr, const int* __restrict__ col,
    const float* __restrict__ a_src, const float* __restrict__ a_dst,
    float* __restrict__ wq, float* __restrict__ den, int N)
{
    int n = blockIdx.x * 4 + (threadIdx.x >> 6);
    if (n >= N) return;
    int lane = threadIdx.x & 63;
    int base = rowptr[n], end = rowptr[n + 1];
    float4 ad = *(const float4*)&a_dst[n * 4];
    float4 ds = {0.0f, 0.0f, 0.0f, 0.0f};
    for (int j = base + lane; j < end; j += 64) {
        int s = col[j];
        float4 as4 = *(const float4*)&a_src[s * 4];
        float l0 = as4.x + ad.x, l1 = as4.y + ad.y;
        float l2 = as4.z + ad.z, l3 = as4.w + ad.w;
        l0 = fmaxf(l0, 0.2f * l0);
        l1 = fmaxf(l1, 0.2f * l1);
        l2 = fmaxf(l2, 0.2f * l2);
        l3 = fmaxf(l3, 0.2f * l3);
        float4 wv = {__expf(l0), __expf(l1), __expf(l2), __expf(l3)};
        *(float4*)&wq[(size_t)j * 4] = wv;
        ds.x += wv.x; ds.y += wv.y; ds.z += wv.z; ds.w += wv.w;
    }
    #pragma unroll
    for (int o = 32; o > 0; o >>= 1) {
        ds.x += __shfl_down(ds.x, o, 64);
        ds.y += __shfl_down(ds.y, o, 64);
        ds.z += __shfl_down(ds.z, o, 64);
        ds.w += __shfl_down(ds.w, o, 64);
    }
    if (lane == 0) *(float4*)&den[n * 4] = ds;
}

// ===== CSR aggregation: wave-per-node weighted sum + bias + ELU ============
// 4 nodes per 256-thread block; wave w owns node blockIdx*4+w. Each lane
// covers 4 consecutive cols (64 lanes x 4 halves = full 256-col fp16 row).
// Weights precomputed; masked unroll-4; no LDS, no __syncthreads.
__global__ __launch_bounds__(256) void gat_agg_csr_kernel(
    const unsigned short* __restrict__ xh,      // fp16 [N x 256]
    const int* __restrict__ rowptr, const int* __restrict__ col,
    const float* __restrict__ wq, const float* __restrict__ den,
    const float* __restrict__ bias,
    unsigned short* __restrict__ outH, unsigned short* __restrict__ outL, int N)
{
    int t = threadIdx.x;
    int n = blockIdx.x * 4 + (t >> 6);
    if (n >= N) return;
    int c = t & 63;
    int h = c >> 4;
    int base = rowptr[n], end = rowptr[n + 1];
    int e1 = end - 1;                      // >= base (self loop guaranteed)
    float inv = 1.0f / den[n * 4 + h];
    const unsigned short* xcol = xh + (c << 2);

    float4 acc = {0.0f, 0.0f, 0.0f, 0.0f};
    for (int j = base; j < end; j += 4) {
        int j1 = j + 1 < e1 ? j + 1 : e1;
        int j2 = j + 2 < e1 ? j + 2 : e1;
        int j3 = j + 3 < e1 ? j + 3 : e1;
        int s0 = col[j], s1 = col[j1], s2 = col[j2], s3 = col[j3];
        float w0 = wq[(size_t)j * 4 + h];
        float w1 = (j + 1 < end) ? wq[(size_t)j1 * 4 + h] : 0.0f;
        float w2 = (j + 2 < end) ? wq[(size_t)j2 * 4 + h] : 0.0f;
        float w3 = (j + 3 < end) ? wq[(size_t)j3 * 4 + h] : 0.0f;
        u16x4 x0 = *(const u16x4*)(xcol + (size_t)s0 * 256);
        u16x4 x1 = *(const u16x4*)(xcol + (size_t)s1 * 256);
        u16x4 x2 = *(const u16x4*)(xcol + (size_t)s2 * 256);
        u16x4 x3 = *(const u16x4*)(xcol + (size_t)s3 * 256);
        acc.x += w0 * h2f(x0[0]) + w1 * h2f(x1[0]) + w2 * h2f(x2[0]) + w3 * h2f(x3[0]);
        acc.y += w0 * h2f(x0[1]) + w1 * h2f(x1[1]) + w2 * h2f(x2[1]) + w3 * h2f(x3[1]);
        acc.z += w0 * h2f(x0[2]) + w1 * h2f(x1[2]) + w2 * h2f(x2[2]) + w3 * h2f(x3[2]);
        acc.w += w0 * h2f(x0[3]) + w1 * h2f(x1[3]) + w2 * h2f(x2[3]) + w3 * h2f(x3[3]);
    }

    float4 bv = *(const float4*)(bias + (c << 2));
    float o0 = acc.x * inv + bv.x;
    float o1 = acc.y * inv + bv.y;
    float o2 = acc.z * inv + bv.z;
    float o3 = acc.w * inv + bv.w;
    o0 = (o0 > 0.0f) ? o0 : (__expf(o0) - 1.0f);
    o1 = (o1 > 0.0f) ? o1 : (__expf(o1) - 1.0f);
    o2 = (o2 > 0.0f) ? o2 : (__expf(o2) - 1.0f);
    o3 = (o3 > 0.0f) ? o3 : (__expf(o3) - 1.0f);
    u16x4 H, L;
    split_hilo(o0, ((unsigned short*)&H)[0], ((unsigned short*)&L)[0]);
    split_hilo(o1, ((unsigned short*)&H)[1], ((unsigned short*)&L)[1]);
    split_hilo(o2, ((unsigned short*)&H)[2], ((unsigned short*)&L)[2]);
    split_hilo(o3, ((unsigned short*)&H)[3], ((unsigned short*)&L)[3]);
    *(u16x4*)(&outH[(size_t)n * 256 + (c << 2)]) = H;
    *(u16x4*)(&outL[(size_t)n * 256 + (c << 2)]) = L;
}

// ===========================================================================

extern "C" void kernel_launch(void* const* d_in, const int* in_sizes, int n_in,
                              void* d_out, int out_size, void* d_ws, size_t ws_size,
                              hipStream_t stream)
{
    const float* node_feats = (const float*)d_in[0];
    const float* edge_attr  = (const float*)d_in[1];
    const float* Wnp = (const float*)d_in[2];
    const float* bnp = (const float*)d_in[3];
    const float* Wep = (const float*)d_in[4];
    const float* bep = (const float*)d_in[5];
    const float* Wg1 = (const float*)d_in[6];
    const float* as1 = (const float*)d_in[7];
    const float* ad1 = (const float*)d_in[8];
    const float* bg1 = (const float*)d_in[9];
    const float* Wg2 = (const float*)d_in[10];
    const float* as2 = (const float*)d_in[11];
    const float* ad2 = (const float*)d_in[12];
    const float* bg2 = (const float*)d_in[13];
    const float* Wo  = (const float*)d_in[14];
    const float* bo  = (const float*)d_in[15];
    const int*   ei  = (const int*)d_in[16];

    const int N = in_sizes[0] / 128;   // 50000
    const int E = in_sizes[16] / 2;    // 800000
    const int* src = ei;
    const int* dst = ei + E;
    const int nchunk = (N + 255) / 256;
    const int EN = E + N;

    typedef unsigned short u16;

    // ---- workspace layout (256B-aligned regions) ----
    char* base = (char*)d_ws;
    size_t off = 0;
    auto alloc = [&](size_t bytes) -> char* {
        char* p = base + off;
        off += (bytes + 255) & ~(size_t)255;
        return p;
    };
    u16* xhh = (u16*)alloc((size_t)N * 256 * 2);           // fp16 xh [N x 256]
    u16* R2  = (u16*)alloc((size_t)N * 512 * 2);           // AcatH, then x3H/x3L
    u16* R3  = (u16*)alloc((size_t)N * 512 * 2);           // AcatL, then x4H/x4L
    float* a_src = (float*)alloc((size_t)N * 4 * 4);
    float* a_dst = (float*)alloc((size_t)N * 4 * 4);
    float* wq    = (float*)alloc((size_t)EN * 4 * 4);      // per-entry weights
    float* den   = (float*)alloc((size_t)N * 4 * 4);       // per-node denominators
    float* Wc    = (float*)alloc(144 * 256 * 4);           // composed front weights
    float* c1    = (float*)alloc(256 * 4);                 // composed front bias
    u16* PcH  = (u16*)alloc(160 * 256 * 2);
    u16* PcL  = (u16*)alloc(160 * 256 * 2);
    u16* Pg2H = (u16*)alloc(256 * 256 * 2);
    u16* Pg2L = (u16*)alloc(256 * 256 * 2);
    u16* PoH  = (u16*)alloc(256 * 256 * 2);
    u16* PoL  = (u16*)alloc(256 * 256 * 2);
    int* cnt       = (int*)alloc((size_t)N * 4);
    int* rowptr    = (int*)alloc((size_t)(N + 1) * 4);
    int* fillptr   = (int*)alloc((size_t)N * 4);
    int* chunk_sum = (int*)alloc((size_t)nchunk * 4);
    int* chunk_off = (int*)alloc((size_t)nchunk * 4);
    int* colv      = (int*)alloc((size_t)EN * 4);
    int* eid       = (int*)alloc((size_t)EN * 4);

    // Acat [N x 160] hi/lo lives in R2/R3 until GAT1 GEMM completes;
    // x3 (agg1 out) / x4 (agg2 out) reuse the same regions afterwards.
    u16* AcatH = R2;
    u16* AcatL = R3;
    u16* x3H = R2;
    u16* x3L = R2 + (size_t)N * 256;
    u16* x4H = R3;
    u16* x4L = R3 + (size_t)N * 256;

    float* out = (float*)d_out;
    dim3 ggrid((N + 63) / 64, 2);

    // ---- CSR build ----
    hipMemsetAsync(cnt, 0, (size_t)N * sizeof(int), stream);
    count_kernel<<<(E + 255) / 256, 256, 0, stream>>>(dst, cnt, E);
    scan1_kernel<<<nchunk, 256, 0, stream>>>(cnt, chunk_sum, N);
    scan2_kernel<<<1, 1, 0, stream>>>(chunk_sum, chunk_off, nchunk);
    scan3_kernel<<<nchunk, 256, 0, stream>>>(cnt, chunk_off, rowptr, fillptr, colv, eid, N);
    fill_kernel<<<(E + 255) / 256, 256, 0, stream>>>(src, dst, fillptr, colv, eid, E);

    // ---- inputs -> Acat; weight compose + packing ----
    nef_csr_kernel<<<(N + 3) / 4, 256, 0, stream>>>(edge_attr, rowptr, eid, AcatH, AcatL, N);
    conv_hilo_strided_kernel<<<((N * 128) / 2 + 255) / 256, 256, 0, stream>>>(
        node_feats, AcatH, AcatL, N * 128);
    compose_w1_kernel<<<145, 256, 0, stream>>>(Wnp, Wep, bnp, bep, Wg1, Wc, c1);
    pack_w_kernel<<<(160 * 256 + 255) / 256, 256, 0, stream>>>(Wc, 144, 160, PcH, PcL);
    pack_w_kernel<<<(256 * 256 + 255) / 256, 256, 0, stream>>>(Wg2, 256, 256, Pg2H, Pg2L);
    pack_w_kernel<<<(256 * 256 + 255) / 256, 256, 0, stream>>>(Wo, 256, 256, PoH, PoL);

    // ---- GAT layer 1: composed GEMM (K=160, +att dots, fp16 out) -> w -> agg
    mfma_gemm_kernel<5, 2, true><<<ggrid, 256, 0, stream>>>(
        AcatH, AcatL, 160, PcH, PcL, c1, nullptr, xhh, nullptr, 256, 0, N,
        as1, ad1, a_src, a_dst);
    edge_w_kernel<<<(N + 3) / 4, 256, 0, stream>>>(
        rowptr, colv, a_src, a_dst, wq, den, N);
    gat_agg_csr_kernel<<<(N + 3) / 4, 256, 0, stream>>>(
        xhh, rowptr, colv, wq, den, bg1, x3H, x3L, N);

    // ---- GAT layer 2 ----
    mfma_gemm_kernel<8, 2, true><<<ggrid, 256, 0, stream>>>(
        x3H, x3L, 256, Pg2H, Pg2L, nullptr, nullptr, xhh, nullptr, 256, 0, N,
        as2, ad2, a_src, a_dst);
    edge_w_kernel<<<(N + 3) / 4, 256, 0, stream>>>(
        rowptr, colv, a_src, a_dst, wq, den, N);
    gat_agg_csr_kernel<<<(N + 3) / 4, 256, 0, stream>>>(
        xhh, rowptr, colv, wq, den, bg2, x4H, x4L, N);

    // ---- out = x4 @ Wo + bo -> d_out (f32) ----
    mfma_gemm_kernel<8, 0, false><<<ggrid, 256, 0, stream>>>(
        x4H, x4L, 256, PoH, PoL, bo, out, nullptr, nullptr, 256, 0, N,
        nullptr, nullptr, nullptr, nullptr);
}

// Round 6
// 571.516 us; speedup vs baseline: 1.2124x; 1.0220x over previous
//
#include <hip/hip_runtime.h>
#include <hip/hip_bf16.h>

// GNN: node_proj + edge scatter_mean/proj -> concat -> GAT(512->4x64) -> ELU
//      -> GAT(256->4x64) -> ELU -> out_proj. ALL tensors float32 (per ref).
// R12: non-agg cleanup (agg is at the ~3.0 TB/s L3 random-gather ceiling,
//      measured consistently R7/R8/R11).
//      (1) scan2: was 1 thread x 196 dependent global loads (~25-40us
//          serial latency); now 1-block 256-thread scan.
//      (2) pack_w x3 launches -> 1 merged kernel.
//      (3) GEMM: A register prefetch with STATIC parity (full t-unroll,
//          ah[2]/al[2], no dynamic copies -- R10's regression was the
//          cur/next movs + runtime indexing). A(t+1) issues under step-t
//          MFMAs; the end-of-step barrier drain finds it landed.

#define HEADS 4

typedef __attribute__((ext_vector_type(8))) short bf16x8;
typedef __attribute__((ext_vector_type(4))) float f32x4;
typedef __attribute__((ext_vector_type(4))) unsigned short u16x4;

__device__ __forceinline__ unsigned short f2b(float v) {
    __hip_bfloat16 b = __float2bfloat16(v);
    return __builtin_bit_cast(unsigned short, b);
}
__device__ __forceinline__ float b2f(unsigned short u) {
    __hip_bfloat16 b = __builtin_bit_cast(__hip_bfloat16, u);
    return __bfloat162float(b);
}
__device__ __forceinline__ void split_hilo(float v, unsigned short& h, unsigned short& l) {
    h = f2b(v);
    l = f2b(v - b2f(h));
}
__device__ __forceinline__ unsigned short f2h(float v) {
    _Float16 h = (_Float16)v;                 // v_cvt_f16_f32, RN
    return __builtin_bit_cast(unsigned short, h);
}
__device__ __forceinline__ float h2f(unsigned short u) {
    return (float)__builtin_bit_cast(_Float16, u);
}
// async global->LDS, 16B per lane; LDS dest is wave-uniform base + lane*16
__device__ __forceinline__ void gl2lds16(const unsigned short* g, unsigned short* l) {
    __builtin_amdgcn_global_load_lds(
        (const __attribute__((address_space(1))) unsigned int*)g,
        (__attribute__((address_space(3))) unsigned int*)l,
        16, 0, 0);
}

// ============================ CSR construction =============================

__global__ __launch_bounds__(256) void count_kernel(
    const int* __restrict__ dst, int* __restrict__ cnt, int E)
{
    int e = blockIdx.x * 256 + threadIdx.x;
    if (e < E) atomicAdd(&cnt[dst[e]], 1);
}

__global__ __launch_bounds__(256) void scan1_kernel(
    const int* __restrict__ cnt, int* __restrict__ chunk_sum, int N)
{
    __shared__ int sd[256];
    int t = threadIdx.x;
    int n = blockIdx.x * 256 + t;
    sd[t] = (n < N) ? (cnt[n] + 1) : 0;
    __syncthreads();
    for (int o = 128; o > 0; o >>= 1) {
        if (t < o) sd[t] += sd[t + o];
        __syncthreads();
    }
    if (t == 0) chunk_sum[blockIdx.x] = sd[0];
}

// R12: 1-block 256-thread scan over chunk sums (was 1 thread x nchunk
// dependent loads ~= 25-40us of serial latency).
__global__ __launch_bounds__(256) void scan2_kernel(
    const int* __restrict__ chunk_sum, int* __restrict__ chunk_off, int nchunk)
{
    __shared__ int sd[256];
    __shared__ int carry;
    int t = threadIdx.x;
    if (t == 0) carry = 0;
    __syncthreads();
    for (int b = 0; b < nchunk; b += 256) {
        int i = b + t;
        int v = (i < nchunk) ? chunk_sum[i] : 0;
        sd[t] = v;
        __syncthreads();
        for (int o = 1; o < 256; o <<= 1) {
            int x = (t >= o) ? sd[t - o] : 0;
            __syncthreads();
            sd[t] += x;
            __syncthreads();
        }
        if (i < nchunk) chunk_off[i] = carry + sd[t] - v;
        __syncthreads();
        if (t == 0) carry += sd[255];
        __syncthreads();
    }
}

__global__ __launch_bounds__(256) void scan3_kernel(
    const int* __restrict__ cnt, const int* __restrict__ chunk_off,
    int* __restrict__ rowptr, int* __restrict__ fillptr,
    int* __restrict__ col, int* __restrict__ eid, int N)
{
    __shared__ int sd[256];
    int t = threadIdx.x;
    int n = blockIdx.x * 256 + t;
    int v = (n < N) ? (cnt[n] + 1) : 0;
    sd[t] = v;
    __syncthreads();
    for (int o = 1; o < 256; o <<= 1) {
        int x = (t >= o) ? sd[t - o] : 0;
        __syncthreads();
        sd[t] += x;
        __syncthreads();
    }
    if (n < N) {
        int incl = sd[t];
        int r = chunk_off[blockIdx.x] + incl - v;
        rowptr[n] = r;
        col[r] = n;        // self loop, first entry
        eid[r] = -1;
        fillptr[n] = r + 1;
        if (n == N - 1) rowptr[N] = chunk_off[blockIdx.x] + incl;
    }
}

__global__ __launch_bounds__(256) void fill_kernel(
    const int* __restrict__ src, const int* __restrict__ dst,
    int* __restrict__ fillptr, int* __restrict__ col, int* __restrict__ eid, int E)
{
    int e = blockIdx.x * 256 + threadIdx.x;
    if (e >= E) return;
    int d = dst[e];
    int p = atomicAdd(&fillptr[d], 1);
    col[p] = src[e];
    eid[p] = e;
}

// ====== edge_attr scatter-mean via CSR -> hi/lo bf16 into Acat cols 128+ ===
// Acat row layout [N x 160]: cols 0..127 nf, 128..143 nef_raw, 144..159 zero.
// 4 nodes per block: wave w handles node blockIdx*4+w.
__global__ __launch_bounds__(256) void nef_csr_kernel(
    const float* __restrict__ ea, const int* __restrict__ rowptr,
    const int* __restrict__ eid,
    unsigned short* __restrict__ AH, unsigned short* __restrict__ AL, int N)
{
    int n = blockIdx.x * 4 + (threadIdx.x >> 6);
    if (n >= N) return;
    int t = threadIdx.x & 63;
    int f = t & 15, g = t >> 4;
    int base = rowptr[n], end = rowptr[n + 1];
    int deg = end - base - 1;
    float acc = 0.0f;
    for (int j = base + 1 + g; j < end; j += 4) {
        int e = eid[j];
        acc += ea[(size_t)e * 16 + f];
    }
    acc += __shfl_down(acc, 32, 64);
    acc += __shfl_down(acc, 16, 64);
    if (t < 16) {
        float v = acc / fmaxf((float)deg, 1.0f);
        unsigned short h, l;
        split_hilo(v, h, l);
        AH[(size_t)n * 160 + 128 + t] = h;
        AL[(size_t)n * 160 + 128 + t] = l;
    } else if (t < 32) {
        AH[(size_t)n * 160 + 128 + t] = 0;
        AL[(size_t)n * 160 + 128 + t] = 0;
    }
}

// ====== convert node_feats f32 [N x 128] -> hi/lo bf16 into Acat cols 0-127
__global__ __launch_bounds__(256) void conv_hilo_strided_kernel(
    const float* __restrict__ X,
    unsigned short* __restrict__ H, unsigned short* __restrict__ L, int total)
{
    int base = (blockIdx.x * 256 + threadIdx.x) * 2;
    if (base >= total) return;
    #pragma unroll
    for (int i = 0; i < 2; i++) {
        int e = base + i;
        int row = e >> 7, c = e & 127;
        unsigned short h, l;
        split_hilo(X[e], h, l);
        H[(size_t)row * 160 + c] = h;
        L[(size_t)row * 160 + c] = l;
    }
}

// ====== compose front-end weights (f32, exact):
// Wc rows 0..127 = Wnp @ Wg1[0:256,:], rows 128..143 = Wep @ Wg1[256:512,:],
// c1[j] = bnp @ Wg1[0:256,j] + bep @ Wg1[256:512,j].
__global__ __launch_bounds__(256) void compose_w1_kernel(
    const float* __restrict__ Wnp, const float* __restrict__ Wep,
    const float* __restrict__ bnp, const float* __restrict__ bep,
    const float* __restrict__ Wg1,
    float* __restrict__ Wc, float* __restrict__ c1)
{
    int idx = blockIdx.x * 256 + threadIdx.x;
    if (idx >= 145 * 256) return;
    int i = idx >> 8, j = idx & 255;
    float s = 0.0f;
    if (i < 128) {
        for (int k = 0; k < 256; k++) s += Wnp[i * 256 + k] * Wg1[(size_t)k * 256 + j];
        Wc[i * 256 + j] = s;
    } else if (i < 144) {
        int ii = i - 128;
        for (int k = 0; k < 256; k++) s += Wep[ii * 256 + k] * Wg1[(size_t)(256 + k) * 256 + j];
        Wc[i * 256 + j] = s;
    } else {
        for (int k = 0; k < 256; k++)
            s += bnp[k] * Wg1[(size_t)k * 256 + j] + bep[k] * Wg1[(size_t)(256 + k) * 256 + j];
        c1[j] = s;
    }
}

// ==== pack 3 weight matrices [K x 256] -> B-fragment order, hi/lo, 1 launch
__device__ __forceinline__ void pack_one(
    const float* __restrict__ W, int K, int KP, int idx,
    unsigned short* __restrict__ Ph, unsigned short* __restrict__ Pl)
{
    int tile = idx >> 9, w = idx & 511, lane = w >> 3, j = w & 7;
    int nk = KP >> 5;
    int ctile = tile / nk, t = tile % nk;
    int k = t * 32 + ((lane >> 4) << 3) + j;
    int n = (ctile << 4) + (lane & 15);
    float v = (k < K) ? W[(size_t)k * 256 + n] : 0.0f;
    unsigned short h, l;
    split_hilo(v, h, l);
    Ph[idx] = h;
    Pl[idx] = l;
}

__global__ __launch_bounds__(256) void pack3_w_kernel(
    const float* __restrict__ Wc,  unsigned short* __restrict__ PcH,  unsigned short* __restrict__ PcL,
    const float* __restrict__ Wg2, unsigned short* __restrict__ Pg2H, unsigned short* __restrict__ Pg2L,
    const float* __restrict__ Wo,  unsigned short* __restrict__ PoH,  unsigned short* __restrict__ PoL)
{
    const int S0 = 160 * 256;            // Wc: K=144, KP=160
    const int S1 = S0 + 256 * 256;       // Wg2
    const int S2 = S1 + 256 * 256;       // Wo
    int idx = blockIdx.x * 256 + threadIdx.x;
    if (idx < S0) {
        pack_one(Wc, 144, 160, idx, PcH, PcL);
    } else if (idx < S1) {
        pack_one(Wg2, 256, 256, idx - S0, Pg2H, Pg2L);
    } else if (idx < S2) {
        pack_one(Wo, 256, 256, idx - S1, PoH, PoL);
    }
}

// ===================== MFMA bf16x3 GEMM ====================================
// C[N x 256] = A[N x KP] @ W[KP x 256] (+bias). Block: 64 rows x 128 cols
// (grid.y=2), 4 waves (wave = 16 rows), 8 col-tiles. B panel double-buffered
// in LDS via global_load_lds; A register-prefetched one k-step ahead with
// STATIC parity (t-loop fully unrolled -> ah[2]/al[2] indices compile-time;
// no dynamic copies). End-of-step __syncthreads drain finds both the B stage
// and the A prefetch already covered by the 24 MFMAs. LDS 32KB -> 5
// blocks/CU; launch_bounds(256,5). OMODE: 0 = f32, 1 = hi/lo bf16, 2 = fp16.
// FUSE_ATT: per-row per-head attention dots of (acc+bias).
template <int KSTEPS, int OMODE, bool FUSE_ATT>
__global__ __launch_bounds__(256, 5) void mfma_gemm_kernel(
    const unsigned short* __restrict__ Ah, const unsigned short* __restrict__ Al,
    int lda,
    const unsigned short* __restrict__ Ph, const unsigned short* __restrict__ Pl,
    const float* __restrict__ bias,
    float* __restrict__ Cf,
    unsigned short* __restrict__ Ch, unsigned short* __restrict__ Cl,
    int ldc, int col_off, int Nrows,
    const float* __restrict__ att_src, const float* __restrict__ att_dst,
    float* __restrict__ a_srcO, float* __restrict__ a_dstO)
{
    __shared__ unsigned short ldsB[2][2][8][512];   // [buf][hi/lo][ctile][elem]
    int tid = threadIdx.x;
    int wave = tid >> 6, lane = tid & 63;
    int quad = lane >> 4, m16 = lane & 15;
    int rowblk = blockIdx.x, colhalf = blockIdx.y;
    int ctile0 = colhalf * 8;

    int row = rowblk * 64 + wave * 16 + m16;
    bool rowok = row < Nrows;
    const unsigned short* arh = Ah + (size_t)row * lda;
    const unsigned short* arl = Al + (size_t)row * lda;

    // wave w stages ctiles {2w, 2w+1} (hi+lo) of k-step t into buf
    auto stage = [&](int t, int buf) {
        #pragma unroll
        for (int q = 0; q < 2; q++) {
            int c = wave * 2 + q;
            size_t gb = ((size_t)((ctile0 + c) * KSTEPS + t)) * 512 + lane * 8;
            gl2lds16(Ph + gb, &ldsB[buf][0][c][0]);
            gl2lds16(Pl + gb, &ldsB[buf][1][c][0]);
        }
    };
    auto loadA = [&](int t, bf16x8& h, bf16x8& l) {
        int k = t * 32 + quad * 8;
        h = (bf16x8){};
        l = (bf16x8){};
        if (rowok) {
            h = *(const bf16x8*)(arh + k);
            l = *(const bf16x8*)(arl + k);
        }
    };

    f32x4 acc[8] = {};
    bf16x8 ah2[2], al2[2];
    loadA(0, ah2[0], al2[0]);
    stage(0, 0);
    __syncthreads();

    #pragma unroll
    for (int t = 0; t < KSTEPS; t++) {
        const int buf = t & 1;
        if (t + 1 < KSTEPS) {
            stage(t + 1, buf ^ 1);
            loadA(t + 1, ah2[(t + 1) & 1], al2[(t + 1) & 1]);   // static after unroll
        }
        #pragma unroll
        for (int c = 0; c < 8; c++) {
            bf16x8 b_h = *(const bf16x8*)&ldsB[buf][0][c][lane * 8];
            bf16x8 b_l = *(const bf16x8*)&ldsB[buf][1][c][lane * 8];
            acc[c] = __builtin_amdgcn_mfma_f32_16x16x32_bf16(ah2[buf], b_h, acc[c], 0, 0, 0);
            acc[c] = __builtin_amdgcn_mfma_f32_16x16x32_bf16(al2[buf], b_h, acc[c], 0, 0, 0);
            acc[c] = __builtin_amdgcn_mfma_f32_16x16x32_bf16(ah2[buf], b_l, acc[c], 0, 0, 0);
        }
        if (t + 1 < KSTEPS) __syncthreads();
    }

    // epilogue: D[row = quad*4 + r][col = m16] within each 16x16 tile
    #pragma unroll
    for (int c = 0; c < 8; c++) {
        int ocol = (ctile0 + c) * 16 + m16;
        float bv = bias ? bias[ocol] : 0.0f;
        #pragma unroll
        for (int r = 0; r < 4; r++) {
            int orow = rowblk * 64 + wave * 16 + quad * 4 + r;
            if (orow >= Nrows) continue;
            float v = acc[c][r] + bv;
            size_t oidx = (size_t)orow * ldc + col_off + ocol;
            if (OMODE == 1) {
                unsigned short h, l;
                split_hilo(v, h, l);
                Ch[oidx] = h;
                Cl[oidx] = l;
            } else if (OMODE == 2) {
                Ch[oidx] = f2h(v);
            } else {
                Cf[oidx] = v;
            }
        }
    }

    if (FUSE_ATT) {
        // per-row (r), per-local-head (hl=c>>2) attention dots of (acc+bias)
        float ps[4][2] = {}, pd[4][2] = {};
        #pragma unroll
        for (int c = 0; c < 8; c++) {
            int ocol = (ctile0 + c) * 16 + m16;
            float bv = bias ? bias[ocol] : 0.0f;
            float asv = att_src[ocol];
            float adv = att_dst[ocol];
            int hl = c >> 2;
            #pragma unroll
            for (int r = 0; r < 4; r++) {
                float v = acc[c][r] + bv;
                ps[r][hl] += v * asv;
                pd[r][hl] += v * adv;
            }
        }
        #pragma unroll
        for (int r = 0; r < 4; r++) {
            #pragma unroll
            for (int hl = 0; hl < 2; hl++) {
                float s = ps[r][hl], d = pd[r][hl];
                #pragma unroll
                for (int o = 8; o > 0; o >>= 1) {
                    s += __shfl_down(s, o, 64);
                    d += __shfl_down(d, o, 64);
                }
                if (m16 == 0) {
                    int orow = rowblk * 64 + wave * 16 + quad * 4 + r;
                    if (orow < Nrows) {
                        int gh = colhalf * 2 + hl;
                        a_srcO[orow * 4 + gh] = s;
                        a_dstO[orow * 4 + gh] = d;
                    }
                }
            }
        }
    }
}

// ===== edge weights: w[j][h] = exp(lrelu(a_src[col[j]][h] + a_dst[n][h])) ==
// 4 nodes/block, wave per node, lane per CSR entry (stride 64). Also
// wave-reduces the per-head denominator.
__global__ __launch_bounds__(256) void edge_w_kernel(
    const int* __restrict__ rowptr, const int* __restrict__ col,
    const float* __restrict__ a_src, const float* __restrict__ a_dst,
    float* __restrict__ wq, float* __restrict__ den, int N)
{
    int n = blockIdx.x * 4 + (threadIdx.x >> 6);
    if (n >= N) return;
    int lane = threadIdx.x & 63;
    int base = rowptr[n], end = rowptr[n + 1];
    float4 ad = *(const float4*)&a_dst[n * 4];
    float4 ds = {0.0f, 0.0f, 0.0f, 0.0f};
    for (int j = base + lane; j < end; j += 64) {
        int s = col[j];
        float4 as4 = *(const float4*)&a_src[s * 4];
        float l0 = as4.x + ad.x, l1 = as4.y + ad.y;
        float l2 = as4.z + ad.z, l3 = as4.w + ad.w;
        l0 = fmaxf(l0, 0.2f * l0);
        l1 = fmaxf(l1, 0.2f * l1);
        l2 = fmaxf(l2, 0.2f * l2);
        l3 = fmaxf(l3, 0.2f * l3);
        float4 wv = {__expf(l0), __expf(l1), __expf(l2), __expf(l3)};
        *(float4*)&wq[(size_t)j * 4] = wv;
        ds.x += wv.x; ds.y += wv.y; ds.z += wv.z; ds.w += wv.w;
    }
    #pragma unroll
    for (int o = 32; o > 0; o >>= 1) {
        ds.x += __shfl_down(ds.x, o, 64);
        ds.y += __shfl_down(ds.y, o, 64);
        ds.z += __shfl_down(ds.z, o, 64);
        ds.w += __shfl_down(ds.w, o, 64);
    }
    if (lane == 0) *(float4*)&den[n * 4] = ds;
}

// ===== CSR aggregation: wave-per-node weighted sum + bias + ELU ============
// 4 nodes per 256-thread block; wave w owns node blockIdx*4+w. Each lane
// covers 4 consecutive cols (64 lanes x 4 halves = full 256-col fp16 row).
// Weights precomputed; masked unroll-4; no LDS, no __syncthreads.
__global__ __launch_bounds__(256) void gat_agg_csr_kernel(
    const unsigned short* __restrict__ xh,      // fp16 [N x 256]
    const int* __restrict__ rowptr, const int* __restrict__ col,
    const float* __restrict__ wq, const float* __restrict__ den,
    const float* __restrict__ bias,
    unsigned short* __restrict__ outH, unsigned short* __restrict__ outL, int N)
{
    int t = threadIdx.x;
    int n = blockIdx.x * 4 + (t >> 6);
    if (n >= N) return;
    int c = t & 63;
    int h = c >> 4;
    int base = rowptr[n], end = rowptr[n + 1];
    int e1 = end - 1;                      // >= base (self loop guaranteed)
    float inv = 1.0f / den[n * 4 + h];
    const unsigned short* xcol = xh + (c << 2);

    float4 acc = {0.0f, 0.0f, 0.0f, 0.0f};
    for (int j = base; j < end; j += 4) {
        int j1 = j + 1 < e1 ? j + 1 : e1;
        int j2 = j + 2 < e1 ? j + 2 : e1;
        int j3 = j + 3 < e1 ? j + 3 : e1;
        int s0 = col[j], s1 = col[j1], s2 = col[j2], s3 = col[j3];
        float w0 = wq[(size_t)j * 4 + h];
        float w1 = (j + 1 < end) ? wq[(size_t)j1 * 4 + h] : 0.0f;
        float w2 = (j + 2 < end) ? wq[(size_t)j2 * 4 + h] : 0.0f;
        float w3 = (j + 3 < end) ? wq[(size_t)j3 * 4 + h] : 0.0f;
        u16x4 x0 = *(const u16x4*)(xcol + (size_t)s0 * 256);
        u16x4 x1 = *(const u16x4*)(xcol + (size_t)s1 * 256);
        u16x4 x2 = *(const u16x4*)(xcol + (size_t)s2 * 256);
        u16x4 x3 = *(const u16x4*)(xcol + (size_t)s3 * 256);
        acc.x += w0 * h2f(x0[0]) + w1 * h2f(x1[0]) + w2 * h2f(x2[0]) + w3 * h2f(x3[0]);
        acc.y += w0 * h2f(x0[1]) + w1 * h2f(x1[1]) + w2 * h2f(x2[1]) + w3 * h2f(x3[1]);
        acc.z += w0 * h2f(x0[2]) + w1 * h2f(x1[2]) + w2 * h2f(x2[2]) + w3 * h2f(x3[2]);
        acc.w += w0 * h2f(x0[3]) + w1 * h2f(x1[3]) + w2 * h2f(x2[3]) + w3 * h2f(x3[3]);
    }

    float4 bv = *(const float4*)(bias + (c << 2));
    float o0 = acc.x * inv + bv.x;
    float o1 = acc.y * inv + bv.y;
    float o2 = acc.z * inv + bv.z;
    float o3 = acc.w * inv + bv.w;
    o0 = (o0 > 0.0f) ? o0 : (__expf(o0) - 1.0f);
    o1 = (o1 > 0.0f) ? o1 : (__expf(o1) - 1.0f);
    o2 = (o2 > 0.0f) ? o2 : (__expf(o2) - 1.0f);
    o3 = (o3 > 0.0f) ? o3 : (__expf(o3) - 1.0f);
    u16x4 H, L;
    split_hilo(o0, ((unsigned short*)&H)[0], ((unsigned short*)&L)[0]);
    split_hilo(o1, ((unsigned short*)&H)[1], ((unsigned short*)&L)[1]);
    split_hilo(o2, ((unsigned short*)&H)[2], ((unsigned short*)&L)[2]);
    split_hilo(o3, ((unsigned short*)&H)[3], ((unsigned short*)&L)[3]);
    *(u16x4*)(&outH[(size_t)n * 256 + (c << 2)]) = H;
    *(u16x4*)(&outL[(size_t)n * 256 + (c << 2)]) = L;
}

// ===========================================================================

extern "C" void kernel_launch(void* const* d_in, const int* in_sizes, int n_in,
                              void* d_out, int out_size, void* d_ws, size_t ws_size,
                              hipStream_t stream)
{
    const float* node_feats = (const float*)d_in[0];
    const float* edge_attr  = (const float*)d_in[1];
    const float* Wnp = (const float*)d_in[2];
    const float* bnp = (const float*)d_in[3];
    const float* Wep = (const float*)d_in[4];
    const float* bep = (const float*)d_in[5];
    const float* Wg1 = (const float*)d_in[6];
    const float* as1 = (const float*)d_in[7];
    const float* ad1 = (const float*)d_in[8];
    const float* bg1 = (const float*)d_in[9];
    const float* Wg2 = (const float*)d_in[10];
    const float* as2 = (const float*)d_in[11];
    const float* ad2 = (const float*)d_in[12];
    const float* bg2 = (const float*)d_in[13];
    const float* Wo  = (const float*)d_in[14];
    const float* bo  = (const float*)d_in[15];
    const int*   ei  = (const int*)d_in[16];

    const int N = in_sizes[0] / 128;   // 50000
    const int E = in_sizes[16] / 2;    // 800000
    const int* src = ei;
    const int* dst = ei + E;
    const int nchunk = (N + 255) / 256;
    const int EN = E + N;

    typedef unsigned short u16;

    // ---- workspace layout (256B-aligned regions) ----
    char* base = (char*)d_ws;
    size_t off = 0;
    auto alloc = [&](size_t bytes) -> char* {
        char* p = base + off;
        off += (bytes + 255) & ~(size_t)255;
        return p;
    };
    u16* xhh = (u16*)alloc((size_t)N * 256 * 2);           // fp16 xh [N x 256]
    u16* R2  = (u16*)alloc((size_t)N * 512 * 2);           // AcatH, then x3H/x3L
    u16* R3  = (u16*)alloc((size_t)N * 512 * 2);           // AcatL, then x4H/x4L
    float* a_src = (float*)alloc((size_t)N * 4 * 4);
    float* a_dst = (float*)alloc((size_t)N * 4 * 4);
    float* wq    = (float*)alloc((size_t)EN * 4 * 4);      // per-entry weights
    float* den   = (float*)alloc((size_t)N * 4 * 4);       // per-node denominators
    float* Wc    = (float*)alloc(144 * 256 * 4);           // composed front weights
    float* c1    = (float*)alloc(256 * 4);                 // composed front bias
    u16* PcH  = (u16*)alloc(160 * 256 * 2);
    u16* PcL  = (u16*)alloc(160 * 256 * 2);
    u16* Pg2H = (u16*)alloc(256 * 256 * 2);
    u16* Pg2L = (u16*)alloc(256 * 256 * 2);
    u16* PoH  = (u16*)alloc(256 * 256 * 2);
    u16* PoL  = (u16*)alloc(256 * 256 * 2);
    int* cnt       = (int*)alloc((size_t)N * 4);
    int* rowptr    = (int*)alloc((size_t)(N + 1) * 4);
    int* fillptr   = (int*)alloc((size_t)N * 4);
    int* chunk_sum = (int*)alloc((size_t)nchunk * 4);
    int* chunk_off = (int*)alloc((size_t)nchunk * 4);
    int* colv      = (int*)alloc((size_t)EN * 4);
    int* eid       = (int*)alloc((size_t)EN * 4);

    // Acat [N x 160] hi/lo lives in R2/R3 until GAT1 GEMM completes;
    // x3 (agg1 out) / x4 (agg2 out) reuse the same regions afterwards.
    u16* AcatH = R2;
    u16* AcatL = R3;
    u16* x3H = R2;
    u16* x3L = R2 + (size_t)N * 256;
    u16* x4H = R3;
    u16* x4L = R3 + (size_t)N * 256;

    float* out = (float*)d_out;
    dim3 ggrid((N + 63) / 64, 2);

    // ---- CSR build ----
    hipMemsetAsync(cnt, 0, (size_t)N * sizeof(int), stream);
    count_kernel<<<(E + 255) / 256, 256, 0, stream>>>(dst, cnt, E);
    scan1_kernel<<<nchunk, 256, 0, stream>>>(cnt, chunk_sum, N);
    scan2_kernel<<<1, 256, 0, stream>>>(chunk_sum, chunk_off, nchunk);
    scan3_kernel<<<nchunk, 256, 0, stream>>>(cnt, chunk_off, rowptr, fillptr, colv, eid, N);
    fill_kernel<<<(E + 255) / 256, 256, 0, stream>>>(src, dst, fillptr, colv, eid, E);

    // ---- inputs -> Acat; weight compose + packing ----
    nef_csr_kernel<<<(N + 3) / 4, 256, 0, stream>>>(edge_attr, rowptr, eid, AcatH, AcatL, N);
    conv_hilo_strided_kernel<<<((N * 128) / 2 + 255) / 256, 256, 0, stream>>>(
        node_feats, AcatH, AcatL, N * 128);
    compose_w1_kernel<<<145, 256, 0, stream>>>(Wnp, Wep, bnp, bep, Wg1, Wc, c1);
    {
        const int total = 160 * 256 + 256 * 256 + 256 * 256;
        pack3_w_kernel<<<(total + 255) / 256, 256, 0, stream>>>(
            Wc, PcH, PcL, Wg2, Pg2H, Pg2L, Wo, PoH, PoL);
    }

    // ---- GAT layer 1: composed GEMM (K=160, +att dots, fp16 out) -> w -> agg
    mfma_gemm_kernel<5, 2, true><<<ggrid, 256, 0, stream>>>(
        AcatH, AcatL, 160, PcH, PcL, c1, nullptr, xhh, nullptr, 256, 0, N,
        as1, ad1, a_src, a_dst);
    edge_w_kernel<<<(N + 3) / 4, 256, 0, stream>>>(
        rowptr, colv, a_src, a_dst, wq, den, N);
    gat_agg_csr_kernel<<<(N + 3) / 4, 256, 0, stream>>>(
        xhh, rowptr, colv, wq, den, bg1, x3H, x3L, N);

    // ---- GAT layer 2 ----
    mfma_gemm_kernel<8, 2, true><<<ggrid, 256, 0, stream>>>(
        x3H, x3L, 256, Pg2H, Pg2L, nullptr, nullptr, xhh, nullptr, 256, 0, N,
        as2, ad2, a_src, a_dst);
    edge_w_kernel<<<(N + 3) / 4, 256, 0, stream>>>(
        rowptr, colv, a_src, a_dst, wq, den, N);
    gat_agg_csr_kernel<<<(N + 3) / 4, 256, 0, stream>>>(
        xhh, rowptr, colv, wq, den, bg2, x4H, x4L, N);

    // ---- out = x4 @ Wo + bo -> d_out (f32) ----
    mfma_gemm_kernel<8, 0, false><<<ggrid, 256, 0, stream>>>(
        x4H, x4L, 256, PoH, PoL, bo, out, nullptr, nullptr, 256, 0, N,
        nullptr, nullptr, nullptr, nullptr);
}

// Round 7
// 540.402 us; speedup vs baseline: 1.2822x; 1.0576x over previous
//
#include <hip/hip_runtime.h>
#include <hip/hip_bf16.h>

// GNN: node_proj + edge scatter_mean/proj -> concat -> GAT(512->4x64) -> ELU
//      -> GAT(256->4x64) -> ELU -> out_proj. ALL tensors float32 (per ref).
// R13: (1) edge_w kernels DELETED: weights are wave-private in agg -> phase-1
//      computes them into LDS (lane-per-edge) inside the same wave; no
//      barrier needed (producer wave == consumer wave). Slow-path inline
//      fallback for degree>128. Kills 2 dispatches + wq/den round-trips.
//      (2) Acat & x3 stored fp16 single (was hilo bf16): their post-smear
//      error contribution is ~1e-4 (analysis in journal); GEMM expands
//      fp16 -> bf16 hi/lo in-register at A-load (VALU at 13%, free).
//      Halves conv/nef/agg1 writes and GEMM1/GEMM2 A-reads. x4 stays hilo
//      (out_proj input sets final precision).
//      Agg remains at the ~3.0 TB/s fabric gather ceiling (R7/R8/R11/R12).

#define HEADS 4

typedef __attribute__((ext_vector_type(8))) short bf16x8;
typedef __attribute__((ext_vector_type(4))) float f32x4;
typedef __attribute__((ext_vector_type(4))) unsigned short u16x4;
typedef __attribute__((ext_vector_type(8))) unsigned short u16x8;

__device__ __forceinline__ unsigned short f2b(float v) {
    __hip_bfloat16 b = __float2bfloat16(v);
    return __builtin_bit_cast(unsigned short, b);
}
__device__ __forceinline__ float b2f(unsigned short u) {
    __hip_bfloat16 b = __builtin_bit_cast(__hip_bfloat16, u);
    return __bfloat162float(b);
}
__device__ __forceinline__ void split_hilo(float v, unsigned short& h, unsigned short& l) {
    h = f2b(v);
    l = f2b(v - b2f(h));
}
__device__ __forceinline__ unsigned short f2h(float v) {
    _Float16 h = (_Float16)v;                 // v_cvt_f16_f32, RN
    return __builtin_bit_cast(unsigned short, h);
}
__device__ __forceinline__ float h2f(unsigned short u) {
    return (float)__builtin_bit_cast(_Float16, u);
}
// async global->LDS, 16B per lane; LDS dest is wave-uniform base + lane*16
__device__ __forceinline__ void gl2lds16(const unsigned short* g, unsigned short* l) {
    __builtin_amdgcn_global_load_lds(
        (const __attribute__((address_space(1))) unsigned int*)g,
        (__attribute__((address_space(3))) unsigned int*)l,
        16, 0, 0);
}

// ============================ CSR construction =============================

__global__ __launch_bounds__(256) void count_kernel(
    const int* __restrict__ dst, int* __restrict__ cnt, int E)
{
    int e = blockIdx.x * 256 + threadIdx.x;
    if (e < E) atomicAdd(&cnt[dst[e]], 1);
}

__global__ __launch_bounds__(256) void scan1_kernel(
    const int* __restrict__ cnt, int* __restrict__ chunk_sum, int N)
{
    __shared__ int sd[256];
    int t = threadIdx.x;
    int n = blockIdx.x * 256 + t;
    sd[t] = (n < N) ? (cnt[n] + 1) : 0;
    __syncthreads();
    for (int o = 128; o > 0; o >>= 1) {
        if (t < o) sd[t] += sd[t + o];
        __syncthreads();
    }
    if (t == 0) chunk_sum[blockIdx.x] = sd[0];
}

// 1-block 256-thread scan over chunk sums
__global__ __launch_bounds__(256) void scan2_kernel(
    const int* __restrict__ chunk_sum, int* __restrict__ chunk_off, int nchunk)
{
    __shared__ int sd[256];
    __shared__ int carry;
    int t = threadIdx.x;
    if (t == 0) carry = 0;
    __syncthreads();
    for (int b = 0; b < nchunk; b += 256) {
        int i = b + t;
        int v = (i < nchunk) ? chunk_sum[i] : 0;
        sd[t] = v;
        __syncthreads();
        for (int o = 1; o < 256; o <<= 1) {
            int x = (t >= o) ? sd[t - o] : 0;
            __syncthreads();
            sd[t] += x;
            __syncthreads();
        }
        if (i < nchunk) chunk_off[i] = carry + sd[t] - v;
        __syncthreads();
        if (t == 0) carry += sd[255];
        __syncthreads();
    }
}

__global__ __launch_bounds__(256) void scan3_kernel(
    const int* __restrict__ cnt, const int* __restrict__ chunk_off,
    int* __restrict__ rowptr, int* __restrict__ fillptr,
    int* __restrict__ col, int* __restrict__ eid, int N)
{
    __shared__ int sd[256];
    int t = threadIdx.x;
    int n = blockIdx.x * 256 + t;
    int v = (n < N) ? (cnt[n] + 1) : 0;
    sd[t] = v;
    __syncthreads();
    for (int o = 1; o < 256; o <<= 1) {
        int x = (t >= o) ? sd[t - o] : 0;
        __syncthreads();
        sd[t] += x;
        __syncthreads();
    }
    if (n < N) {
        int incl = sd[t];
        int r = chunk_off[blockIdx.x] + incl - v;
        rowptr[n] = r;
        col[r] = n;        // self loop, first entry
        eid[r] = -1;
        fillptr[n] = r + 1;
        if (n == N - 1) rowptr[N] = chunk_off[blockIdx.x] + incl;
    }
}

__global__ __launch_bounds__(256) void fill_kernel(
    const int* __restrict__ src, const int* __restrict__ dst,
    int* __restrict__ fillptr, int* __restrict__ col, int* __restrict__ eid, int E)
{
    int e = blockIdx.x * 256 + threadIdx.x;
    if (e >= E) return;
    int d = dst[e];
    int p = atomicAdd(&fillptr[d], 1);
    col[p] = src[e];
    eid[p] = e;
}

// ====== edge_attr scatter-mean via CSR -> fp16 into Acat cols 128+ =========
// Acat row layout [N x 160] fp16: 0..127 nf, 128..143 nef_raw, 144..159 zero.
__global__ __launch_bounds__(256) void nef_csr_kernel(
    const float* __restrict__ ea, const int* __restrict__ rowptr,
    const int* __restrict__ eid,
    unsigned short* __restrict__ AF, int N)
{
    int n = blockIdx.x * 4 + (threadIdx.x >> 6);
    if (n >= N) return;
    int t = threadIdx.x & 63;
    int f = t & 15, g = t >> 4;
    int base = rowptr[n], end = rowptr[n + 1];
    int deg = end - base - 1;
    float acc = 0.0f;
    for (int j = base + 1 + g; j < end; j += 4) {
        int e = eid[j];
        acc += ea[(size_t)e * 16 + f];
    }
    acc += __shfl_down(acc, 32, 64);
    acc += __shfl_down(acc, 16, 64);
    if (t < 16) {
        float v = acc / fmaxf((float)deg, 1.0f);
        AF[(size_t)n * 160 + 128 + t] = f2h(v);
    } else if (t < 32) {
        AF[(size_t)n * 160 + 128 + t] = 0;
    }
}

// ====== convert node_feats f32 [N x 128] -> fp16 into Acat cols 0-127 ======
__global__ __launch_bounds__(256) void conv_f16_strided_kernel(
    const float* __restrict__ X, unsigned short* __restrict__ AF, int total)
{
    int base = (blockIdx.x * 256 + threadIdx.x) * 2;
    if (base >= total) return;
    #pragma unroll
    for (int i = 0; i < 2; i++) {
        int e = base + i;
        int row = e >> 7, c = e & 127;
        AF[(size_t)row * 160 + c] = f2h(X[e]);
    }
}

// ====== compose front-end weights (f32, exact):
// Wc rows 0..127 = Wnp @ Wg1[0:256,:], rows 128..143 = Wep @ Wg1[256:512,:],
// c1[j] = bnp @ Wg1[0:256,j] + bep @ Wg1[256:512,j].
__global__ __launch_bounds__(256) void compose_w1_kernel(
    const float* __restrict__ Wnp, const float* __restrict__ Wep,
    const float* __restrict__ bnp, const float* __restrict__ bep,
    const float* __restrict__ Wg1,
    float* __restrict__ Wc, float* __restrict__ c1)
{
    int idx = blockIdx.x * 256 + threadIdx.x;
    if (idx >= 145 * 256) return;
    int i = idx >> 8, j = idx & 255;
    float s = 0.0f;
    if (i < 128) {
        for (int k = 0; k < 256; k++) s += Wnp[i * 256 + k] * Wg1[(size_t)k * 256 + j];
        Wc[i * 256 + j] = s;
    } else if (i < 144) {
        int ii = i - 128;
        for (int k = 0; k < 256; k++) s += Wep[ii * 256 + k] * Wg1[(size_t)(256 + k) * 256 + j];
        Wc[i * 256 + j] = s;
    } else {
        for (int k = 0; k < 256; k++)
            s += bnp[k] * Wg1[(size_t)k * 256 + j] + bep[k] * Wg1[(size_t)(256 + k) * 256 + j];
        c1[j] = s;
    }
}

// ==== pack 3 weight matrices [K x 256] -> B-fragment order, hi/lo, 1 launch
__device__ __forceinline__ void pack_one(
    const float* __restrict__ W, int K, int KP, int idx,
    unsigned short* __restrict__ Ph, unsigned short* __restrict__ Pl)
{
    int tile = idx >> 9, w = idx & 511, lane = w >> 3, j = w & 7;
    int nk = KP >> 5;
    int ctile = tile / nk, t = tile % nk;
    int k = t * 32 + ((lane >> 4) << 3) + j;
    int n = (ctile << 4) + (lane & 15);
    float v = (k < K) ? W[(size_t)k * 256 + n] : 0.0f;
    unsigned short h, l;
    split_hilo(v, h, l);
    Ph[idx] = h;
    Pl[idx] = l;
}

__global__ __launch_bounds__(256) void pack3_w_kernel(
    const float* __restrict__ Wc,  unsigned short* __restrict__ PcH,  unsigned short* __restrict__ PcL,
    const float* __restrict__ Wg2, unsigned short* __restrict__ Pg2H, unsigned short* __restrict__ Pg2L,
    const float* __restrict__ Wo,  unsigned short* __restrict__ PoH,  unsigned short* __restrict__ PoL)
{
    const int S0 = 160 * 256;            // Wc: K=144, KP=160
    const int S1 = S0 + 256 * 256;       // Wg2
    const int S2 = S1 + 256 * 256;       // Wo
    int idx = blockIdx.x * 256 + threadIdx.x;
    if (idx < S0) {
        pack_one(Wc, 144, 160, idx, PcH, PcL);
    } else if (idx < S1) {
        pack_one(Wg2, 256, 256, idx - S0, Pg2H, Pg2L);
    } else if (idx < S2) {
        pack_one(Wo, 256, 256, idx - S1, PoH, PoL);
    }
}

// ===================== MFMA bf16x3 GEMM ====================================
// C[N x 256] = A[N x KP] @ W[KP x 256] (+bias). Block: 64 rows x 128 cols
// (grid.y=2), 4 waves (wave = 16 rows), 8 col-tiles. B panel double-buffered
// in LDS via global_load_lds; A register-prefetched one step ahead (static
// parity). AMODE: 0 = hilo bf16 (Ah,Al), 1 = fp16 single (Ah; expanded to
// bf16 hi/lo in-register -- VALU is idle, traffic halves). OMODE: 0 = f32,
// 1 = hilo bf16, 2 = fp16. FUSE_ATT: per-row per-head dots of (acc+bias).
template <int KSTEPS, int AMODE, int OMODE, bool FUSE_ATT>
__global__ __launch_bounds__(256, 5) void mfma_gemm_kernel(
    const unsigned short* __restrict__ Ah, const unsigned short* __restrict__ Al,
    int lda,
    const unsigned short* __restrict__ Ph, const unsigned short* __restrict__ Pl,
    const float* __restrict__ bias,
    float* __restrict__ Cf,
    unsigned short* __restrict__ Ch, unsigned short* __restrict__ Cl,
    int ldc, int col_off, int Nrows,
    const float* __restrict__ att_src, const float* __restrict__ att_dst,
    float* __restrict__ a_srcO, float* __restrict__ a_dstO)
{
    __shared__ unsigned short ldsB[2][2][8][512];   // [buf][hi/lo][ctile][elem]
    int tid = threadIdx.x;
    int wave = tid >> 6, lane = tid & 63;
    int quad = lane >> 4, m16 = lane & 15;
    int rowblk = blockIdx.x, colhalf = blockIdx.y;
    int ctile0 = colhalf * 8;

    int row = rowblk * 64 + wave * 16 + m16;
    bool rowok = row < Nrows;
    const unsigned short* arh = Ah + (size_t)row * lda;
    const unsigned short* arl = (AMODE == 0) ? (Al + (size_t)row * lda) : nullptr;

    auto stage = [&](int t, int buf) {
        #pragma unroll
        for (int q = 0; q < 2; q++) {
            int c = wave * 2 + q;
            size_t gb = ((size_t)((ctile0 + c) * KSTEPS + t)) * 512 + lane * 8;
            gl2lds16(Ph + gb, &ldsB[buf][0][c][0]);
            gl2lds16(Pl + gb, &ldsB[buf][1][c][0]);
        }
    };
    auto loadA = [&](int t, bf16x8& h, bf16x8& l) {
        int k = t * 32 + quad * 8;
        h = (bf16x8){};
        l = (bf16x8){};
        if (rowok) {
            if (AMODE == 0) {
                h = *(const bf16x8*)(arh + k);
                l = *(const bf16x8*)(arl + k);
            } else {
                u16x8 v = *(const u16x8*)(arh + k);   // fp16
                #pragma unroll
                for (int i = 0; i < 8; i++) {
                    float f = h2f(v[i]);
                    unsigned short hh, ll;
                    split_hilo(f, hh, ll);
                    ((unsigned short*)&h)[i] = hh;
                    ((unsigned short*)&l)[i] = ll;
                }
            }
        }
    };

    f32x4 acc[8] = {};
    bf16x8 ah2[2], al2[2];
    loadA(0, ah2[0], al2[0]);
    stage(0, 0);
    __syncthreads();

    #pragma unroll
    for (int t = 0; t < KSTEPS; t++) {
        const int buf = t & 1;
        if (t + 1 < KSTEPS) {
            stage(t + 1, buf ^ 1);
            loadA(t + 1, ah2[(t + 1) & 1], al2[(t + 1) & 1]);   // static after unroll
        }
        #pragma unroll
        for (int c = 0; c < 8; c++) {
            bf16x8 b_h = *(const bf16x8*)&ldsB[buf][0][c][lane * 8];
            bf16x8 b_l = *(const bf16x8*)&ldsB[buf][1][c][lane * 8];
            acc[c] = __builtin_amdgcn_mfma_f32_16x16x32_bf16(ah2[buf], b_h, acc[c], 0, 0, 0);
            acc[c] = __builtin_amdgcn_mfma_f32_16x16x32_bf16(al2[buf], b_h, acc[c], 0, 0, 0);
            acc[c] = __builtin_amdgcn_mfma_f32_16x16x32_bf16(ah2[buf], b_l, acc[c], 0, 0, 0);
        }
        if (t + 1 < KSTEPS) __syncthreads();
    }

    // epilogue: D[row = quad*4 + r][col = m16] within each 16x16 tile
    #pragma unroll
    for (int c = 0; c < 8; c++) {
        int ocol = (ctile0 + c) * 16 + m16;
        float bv = bias ? bias[ocol] : 0.0f;
        #pragma unroll
        for (int r = 0; r < 4; r++) {
            int orow = rowblk * 64 + wave * 16 + quad * 4 + r;
            if (orow >= Nrows) continue;
            float v = acc[c][r] + bv;
            size_t oidx = (size_t)orow * ldc + col_off + ocol;
            if (OMODE == 1) {
                unsigned short h, l;
                split_hilo(v, h, l);
                Ch[oidx] = h;
                Cl[oidx] = l;
            } else if (OMODE == 2) {
                Ch[oidx] = f2h(v);
            } else {
                Cf[oidx] = v;
            }
        }
    }

    if (FUSE_ATT) {
        float ps[4][2] = {}, pd[4][2] = {};
        #pragma unroll
        for (int c = 0; c < 8; c++) {
            int ocol = (ctile0 + c) * 16 + m16;
            float bv = bias ? bias[ocol] : 0.0f;
            float asv = att_src[ocol];
            float adv = att_dst[ocol];
            int hl = c >> 2;
            #pragma unroll
            for (int r = 0; r < 4; r++) {
                float v = acc[c][r] + bv;
                ps[r][hl] += v * asv;
                pd[r][hl] += v * adv;
            }
        }
        #pragma unroll
        for (int r = 0; r < 4; r++) {
            #pragma unroll
            for (int hl = 0; hl < 2; hl++) {
                float s = ps[r][hl], d = pd[r][hl];
                #pragma unroll
                for (int o = 8; o > 0; o >>= 1) {
                    s += __shfl_down(s, o, 64);
                    d += __shfl_down(d, o, 64);
                }
                if (m16 == 0) {
                    int orow = rowblk * 64 + wave * 16 + quad * 4 + r;
                    if (orow < Nrows) {
                        int gh = colhalf * 2 + hl;
                        a_srcO[orow * 4 + gh] = s;
                        a_dstO[orow * 4 + gh] = d;
                    }
                }
            }
        }
    }
}

// ===== CSR aggregation: wave-per-node; fused weight phase + weighted sum ===
// 4 nodes per 256-thread block; wave w owns node blockIdx*4+w.
// Phase 1 (fast path, deg<=128): lane-per-edge computes all 4 head weights
// into wave-private LDS + shuffle-reduced denominator. No barrier needed:
// producer wave == consumer wave. Slow path (deg>128, ~never): inline
// R8-style redundant computation. Phase 2: each lane covers 4 consecutive
// cols; masked unroll-4 gather-accumulate; weights broadcast from LDS.
// OUTF16: true -> single fp16 store (x3); false -> hilo bf16 (x4).
template <bool OUTF16>
__global__ __launch_bounds__(256) void gat_agg_csr_kernel(
    const unsigned short* __restrict__ xh,      // fp16 [N x 256]
    const int* __restrict__ rowptr, const int* __restrict__ col,
    const float* __restrict__ a_src, const float* __restrict__ a_dst,
    const float* __restrict__ bias,
    unsigned short* __restrict__ outA, unsigned short* __restrict__ outB, int N)
{
    __shared__ float wlds[4][128][HEADS];       // 8 KB, wave-private rows
    int t = threadIdx.x;
    int wv = t >> 6;
    int n = blockIdx.x * 4 + wv;
    if (n >= N) return;
    int c = t & 63;
    int h = c >> 4;
    int base = rowptr[n], end = rowptr[n + 1];
    int deg = end - base;                       // >= 1 (self loop)
    int e1 = end - 1;
    float4 ad = *(const float4*)&a_dst[n * 4];
    float adh = (h == 0) ? ad.x : (h == 1) ? ad.y : (h == 2) ? ad.z : ad.w;
    const unsigned short* xcol = xh + (c << 2);

    float4 acc = {0.0f, 0.0f, 0.0f, 0.0f};
    float den = 0.0f;

    if (deg <= 128) {
        // ---- phase 1: weights into LDS (lane-per-edge) + denominator ----
        float4 ds = {0.0f, 0.0f, 0.0f, 0.0f};
        for (int j = base + c; j < end; j += 64) {
            int s = col[j];
            float4 as4 = *(const float4*)&a_src[s * 4];
            float l0 = as4.x + ad.x, l1 = as4.y + ad.y;
            float l2 = as4.z + ad.z, l3 = as4.w + ad.w;
            l0 = fmaxf(l0, 0.2f * l0);
            l1 = fmaxf(l1, 0.2f * l1);
            l2 = fmaxf(l2, 0.2f * l2);
            l3 = fmaxf(l3, 0.2f * l3);
            float4 wv4 = {__expf(l0), __expf(l1), __expf(l2), __expf(l3)};
            *(float4*)&wlds[wv][j - base][0] = wv4;
            ds.x += wv4.x; ds.y += wv4.y; ds.z += wv4.z; ds.w += wv4.w;
        }
        #pragma unroll
        for (int o = 32; o > 0; o >>= 1) {
            ds.x += __shfl_down(ds.x, o, 64);
            ds.y += __shfl_down(ds.y, o, 64);
            ds.z += __shfl_down(ds.z, o, 64);
            ds.w += __shfl_down(ds.w, o, 64);
        }
        float d0 = __shfl(ds.x, 0, 64);
        float d1 = __shfl(ds.y, 0, 64);
        float d2 = __shfl(ds.z, 0, 64);
        float d3 = __shfl(ds.w, 0, 64);
        den = (h == 0) ? d0 : (h == 1) ? d1 : (h == 2) ? d2 : d3;

        // ---- phase 2: gather-accumulate, weights broadcast from LDS ----
        for (int j = base; j < end; j += 4) {
            int j1 = j + 1 < e1 ? j + 1 : e1;
            int j2 = j + 2 < e1 ? j + 2 : e1;
            int j3 = j + 3 < e1 ? j + 3 : e1;
            int s0 = col[j], s1 = col[j1], s2 = col[j2], s3 = col[j3];
            float w0 = wlds[wv][j - base][h];
            float w1 = (j + 1 < end) ? wlds[wv][j1 - base][h] : 0.0f;
            float w2 = (j + 2 < end) ? wlds[wv][j2 - base][h] : 0.0f;
            float w3 = (j + 3 < end) ? wlds[wv][j3 - base][h] : 0.0f;
            u16x4 x0 = *(const u16x4*)(xcol + (size_t)s0 * 256);
            u16x4 x1 = *(const u16x4*)(xcol + (size_t)s1 * 256);
            u16x4 x2 = *(const u16x4*)(xcol + (size_t)s2 * 256);
            u16x4 x3 = *(const u16x4*)(xcol + (size_t)s3 * 256);
            acc.x += w0 * h2f(x0[0]) + w1 * h2f(x1[0]) + w2 * h2f(x2[0]) + w3 * h2f(x3[0]);
            acc.y += w0 * h2f(x0[1]) + w1 * h2f(x1[1]) + w2 * h2f(x2[1]) + w3 * h2f(x3[1]);
            acc.z += w0 * h2f(x0[2]) + w1 * h2f(x1[2]) + w2 * h2f(x2[2]) + w3 * h2f(x3[2]);
            acc.w += w0 * h2f(x0[3]) + w1 * h2f(x1[3]) + w2 * h2f(x2[3]) + w3 * h2f(x3[3]);
        }
    } else {
        // ---- slow path (deg > 128, practically never): inline weights ----
        for (int j = base; j < end; j += 4) {
            int j1 = j + 1 < e1 ? j + 1 : e1;
            int j2 = j + 2 < e1 ? j + 2 : e1;
            int j3 = j + 3 < e1 ? j + 3 : e1;
            int s0 = col[j], s1 = col[j1], s2 = col[j2], s3 = col[j3];
            float l0 = a_src[s0 * 4 + h] + adh;
            float l1 = a_src[s1 * 4 + h] + adh;
            float l2 = a_src[s2 * 4 + h] + adh;
            float l3 = a_src[s3 * 4 + h] + adh;
            l0 = fmaxf(l0, 0.2f * l0);
            l1 = fmaxf(l1, 0.2f * l1);
            l2 = fmaxf(l2, 0.2f * l2);
            l3 = fmaxf(l3, 0.2f * l3);
            float w0 = __expf(l0);
            float w1 = (j + 1 < end) ? __expf(l1) : 0.0f;
            float w2 = (j + 2 < end) ? __expf(l2) : 0.0f;
            float w3 = (j + 3 < end) ? __expf(l3) : 0.0f;
            u16x4 x0 = *(const u16x4*)(xcol + (size_t)s0 * 256);
            u16x4 x1 = *(const u16x4*)(xcol + (size_t)s1 * 256);
            u16x4 x2 = *(const u16x4*)(xcol + (size_t)s2 * 256);
            u16x4 x3 = *(const u16x4*)(xcol + (size_t)s3 * 256);
            den += (w0 + w1) + (w2 + w3);
            acc.x += w0 * h2f(x0[0]) + w1 * h2f(x1[0]) + w2 * h2f(x2[0]) + w3 * h2f(x3[0]);
            acc.y += w0 * h2f(x0[1]) + w1 * h2f(x1[1]) + w2 * h2f(x2[1]) + w3 * h2f(x3[1]);
            acc.z += w0 * h2f(x0[2]) + w1 * h2f(x1[2]) + w2 * h2f(x2[2]) + w3 * h2f(x3[2]);
            acc.w += w0 * h2f(x0[3]) + w1 * h2f(x1[3]) + w2 * h2f(x2[3]) + w3 * h2f(x3[3]);
        }
    }

    float inv = 1.0f / den;
    float4 bv = *(const float4*)(bias + (c << 2));
    float o0 = acc.x * inv + bv.x;
    float o1 = acc.y * inv + bv.y;
    float o2 = acc.z * inv + bv.z;
    float o3 = acc.w * inv + bv.w;
    o0 = (o0 > 0.0f) ? o0 : (__expf(o0) - 1.0f);
    o1 = (o1 > 0.0f) ? o1 : (__expf(o1) - 1.0f);
    o2 = (o2 > 0.0f) ? o2 : (__expf(o2) - 1.0f);
    o3 = (o3 > 0.0f) ? o3 : (__expf(o3) - 1.0f);
    if (OUTF16) {
        u16x4 H;
        H[0] = f2h(o0); H[1] = f2h(o1); H[2] = f2h(o2); H[3] = f2h(o3);
        *(u16x4*)(&outA[(size_t)n * 256 + (c << 2)]) = H;
    } else {
        u16x4 H, L;
        split_hilo(o0, ((unsigned short*)&H)[0], ((unsigned short*)&L)[0]);
        split_hilo(o1, ((unsigned short*)&H)[1], ((unsigned short*)&L)[1]);
        split_hilo(o2, ((unsigned short*)&H)[2], ((unsigned short*)&L)[2]);
        split_hilo(o3, ((unsigned short*)&H)[3], ((unsigned short*)&L)[3]);
        *(u16x4*)(&outA[(size_t)n * 256 + (c << 2)]) = H;
        *(u16x4*)(&outB[(size_t)n * 256 + (c << 2)]) = L;
    }
}

// ===========================================================================

extern "C" void kernel_launch(void* const* d_in, const int* in_sizes, int n_in,
                              void* d_out, int out_size, void* d_ws, size_t ws_size,
                              hipStream_t stream)
{
    const float* node_feats = (const float*)d_in[0];
    const float* edge_attr  = (const float*)d_in[1];
    const float* Wnp = (const float*)d_in[2];
    const float* bnp = (const float*)d_in[3];
    const float* Wep = (const float*)d_in[4];
    const float* bep = (const float*)d_in[5];
    const float* Wg1 = (const float*)d_in[6];
    const float* as1 = (const float*)d_in[7];
    const float* ad1 = (const float*)d_in[8];
    const float* bg1 = (const float*)d_in[9];
    const float* Wg2 = (const float*)d_in[10];
    const float* as2 = (const float*)d_in[11];
    const float* ad2 = (const float*)d_in[12];
    const float* bg2 = (const float*)d_in[13];
    const float* Wo  = (const float*)d_in[14];
    const float* bo  = (const float*)d_in[15];
    const int*   ei  = (const int*)d_in[16];

    const int N = in_sizes[0] / 128;   // 50000
    const int E = in_sizes[16] / 2;    // 800000
    const int* src = ei;
    const int* dst = ei + E;
    const int nchunk = (N + 255) / 256;
    const int EN = E + N;

    typedef unsigned short u16;

    // ---- workspace layout (256B-aligned regions) ----
    char* base = (char*)d_ws;
    size_t off = 0;
    auto alloc = [&](size_t bytes) -> char* {
        char* p = base + off;
        off += (bytes + 255) & ~(size_t)255;
        return p;
    };
    u16* xhh = (u16*)alloc((size_t)N * 256 * 2);           // fp16 xh [N x 256]
    u16* R2  = (u16*)alloc((size_t)N * 512 * 2);           // AcatF then x3F
    u16* R3  = (u16*)alloc((size_t)N * 512 * 2);           // x4H/x4L (hilo)
    float* a_src = (float*)alloc((size_t)N * 4 * 4);
    float* a_dst = (float*)alloc((size_t)N * 4 * 4);
    float* Wc    = (float*)alloc(144 * 256 * 4);           // composed front weights
    float* c1    = (float*)alloc(256 * 4);                 // composed front bias
    u16* PcH  = (u16*)alloc(160 * 256 * 2);
    u16* PcL  = (u16*)alloc(160 * 256 * 2);
    u16* Pg2H = (u16*)alloc(256 * 256 * 2);
    u16* Pg2L = (u16*)alloc(256 * 256 * 2);
    u16* PoH  = (u16*)alloc(256 * 256 * 2);
    u16* PoL  = (u16*)alloc(256 * 256 * 2);
    int* cnt       = (int*)alloc((size_t)N * 4);
    int* rowptr    = (int*)alloc((size_t)(N + 1) * 4);
    int* fillptr   = (int*)alloc((size_t)N * 4);
    int* chunk_sum = (int*)alloc((size_t)nchunk * 4);
    int* chunk_off = (int*)alloc((size_t)nchunk * 4);
    int* colv      = (int*)alloc((size_t)EN * 4);
    int* eid       = (int*)alloc((size_t)EN * 4);

    // AcatF [N x 160] fp16 lives in R2 until GAT1 GEMM completes; x3F
    // (agg1 out, [N x 256] fp16) reuses R2 afterwards. x4 hilo in R3.
    u16* AcatF = R2;
    u16* x3F   = R2;
    u16* x4H = R3;
    u16* x4L = R3 + (size_t)N * 256;

    float* out = (float*)d_out;
    dim3 ggrid((N + 63) / 64, 2);

    // ---- CSR build ----
    hipMemsetAsync(cnt, 0, (size_t)N * sizeof(int), stream);
    count_kernel<<<(E + 255) / 256, 256, 0, stream>>>(dst, cnt, E);
    scan1_kernel<<<nchunk, 256, 0, stream>>>(cnt, chunk_sum, N);
    scan2_kernel<<<1, 256, 0, stream>>>(chunk_sum, chunk_off, nchunk);
    scan3_kernel<<<nchunk, 256, 0, stream>>>(cnt, chunk_off, rowptr, fillptr, colv, eid, N);
    fill_kernel<<<(E + 255) / 256, 256, 0, stream>>>(src, dst, fillptr, colv, eid, E);

    // ---- inputs -> Acat (fp16); weight compose + packing ----
    nef_csr_kernel<<<(N + 3) / 4, 256, 0, stream>>>(edge_attr, rowptr, eid, AcatF, N);
    conv_f16_strided_kernel<<<((N * 128) / 2 + 255) / 256, 256, 0, stream>>>(
        node_feats, AcatF, N * 128);
    compose_w1_kernel<<<145, 256, 0, stream>>>(Wnp, Wep, bnp, bep, Wg1, Wc, c1);
    {
        const int total = 160 * 256 + 256 * 256 + 256 * 256;
        pack3_w_kernel<<<(total + 255) / 256, 256, 0, stream>>>(
            Wc, PcH, PcL, Wg2, Pg2H, Pg2L, Wo, PoH, PoL);
    }

    // ---- GAT layer 1: composed GEMM (K=160, fp16 A, +att dots) -> agg ----
    mfma_gemm_kernel<5, 1, 2, true><<<ggrid, 256, 0, stream>>>(
        AcatF, nullptr, 160, PcH, PcL, c1, nullptr, xhh, nullptr, 256, 0, N,
        as1, ad1, a_src, a_dst);
    gat_agg_csr_kernel<true><<<(N + 3) / 4, 256, 0, stream>>>(
        xhh, rowptr, colv, a_src, a_dst, bg1, x3F, nullptr, N);

    // ---- GAT layer 2 (fp16 A) ----
    mfma_gemm_kernel<8, 1, 2, true><<<ggrid, 256, 0, stream>>>(
        x3F, nullptr, 256, Pg2H, Pg2L, nullptr, nullptr, xhh, nullptr, 256, 0, N,
        as2, ad2, a_src, a_dst);
    gat_agg_csr_kernel<false><<<(N + 3) / 4, 256, 0, stream>>>(
        xhh, rowptr, colv, a_src, a_dst, bg2, x4H, x4L, N);

    // ---- out = x4 @ Wo + bo -> d_out (f32), hilo A ----
    mfma_gemm_kernel<8, 0, 0, false><<<ggrid, 256, 0, stream>>>(
        x4H, x4L, 256, PoH, PoL, bo, out, nullptr, nullptr, 256, 0, N,
        nullptr, nullptr, nullptr, nullptr);
}

// Round 8
// 538.997 us; speedup vs baseline: 1.2855x; 1.0026x over previous
//
#include <hip/hip_runtime.h>
#include <hip/hip_bf16.h>

// GNN: node_proj + edge scatter_mean/proj -> concat -> GAT(512->4x64) -> ELU
//      -> GAT(256->4x64) -> ELU -> out_proj. ALL tensors float32 (per ref).
// R14: full switch bf16x3 -> fp16 MFMA. A is already fp16 (R13), so:
//      GEMM1/2: A fp16 single as DIRECT MFMA operand (kills the 8x
//      split_hilo VALU expansion per A-load) x B fp16-hilo (22-bit
//      effective, better than bf16-hilo's ~17) = 2 MFMAs/ctile/kstep
//      (was 3). GEMM3: x4 + Wo fp16-hilo, 3 MFMAs (same count, more
//      precision). Agg unchanged -- pegged at the ~3.0 TB/s fabric
//      gather ceiling (R7/R8/R11/R12/R13, 210MB/70us per dispatch).

#define HEADS 4

typedef __attribute__((ext_vector_type(8))) _Float16 f16x8;
typedef __attribute__((ext_vector_type(4))) float f32x4;
typedef __attribute__((ext_vector_type(4))) unsigned short u16x4;
typedef __attribute__((ext_vector_type(8))) unsigned short u16x8;

__device__ __forceinline__ unsigned short f2h(float v) {
    _Float16 h = (_Float16)v;                 // v_cvt_f16_f32, RN
    return __builtin_bit_cast(unsigned short, h);
}
__device__ __forceinline__ float h2f(unsigned short u) {
    return (float)__builtin_bit_cast(_Float16, u);
}
// fp16 hi/lo split: h + l reproduces v to ~22 mantissa bits
__device__ __forceinline__ void split_hilo16(float v, unsigned short& h, unsigned short& l) {
    h = f2h(v);
    l = f2h(v - h2f(h));
}
// async global->LDS, 16B per lane; LDS dest is wave-uniform base + lane*16
__device__ __forceinline__ void gl2lds16(const unsigned short* g, unsigned short* l) {
    __builtin_amdgcn_global_load_lds(
        (const __attribute__((address_space(1))) unsigned int*)g,
        (__attribute__((address_space(3))) unsigned int*)l,
        16, 0, 0);
}

// ============================ CSR construction =============================

__global__ __launch_bounds__(256) void count_kernel(
    const int* __restrict__ dst, int* __restrict__ cnt, int E)
{
    int e = blockIdx.x * 256 + threadIdx.x;
    if (e < E) atomicAdd(&cnt[dst[e]], 1);
}

__global__ __launch_bounds__(256) void scan1_kernel(
    const int* __restrict__ cnt, int* __restrict__ chunk_sum, int N)
{
    __shared__ int sd[256];
    int t = threadIdx.x;
    int n = blockIdx.x * 256 + t;
    sd[t] = (n < N) ? (cnt[n] + 1) : 0;
    __syncthreads();
    for (int o = 128; o > 0; o >>= 1) {
        if (t < o) sd[t] += sd[t + o];
        __syncthreads();
    }
    if (t == 0) chunk_sum[blockIdx.x] = sd[0];
}

// 1-block 256-thread scan over chunk sums
__global__ __launch_bounds__(256) void scan2_kernel(
    const int* __restrict__ chunk_sum, int* __restrict__ chunk_off, int nchunk)
{
    __shared__ int sd[256];
    __shared__ int carry;
    int t = threadIdx.x;
    if (t == 0) carry = 0;
    __syncthreads();
    for (int b = 0; b < nchunk; b += 256) {
        int i = b + t;
        int v = (i < nchunk) ? chunk_sum[i] : 0;
        sd[t] = v;
        __syncthreads();
        for (int o = 1; o < 256; o <<= 1) {
            int x = (t >= o) ? sd[t - o] : 0;
            __syncthreads();
            sd[t] += x;
            __syncthreads();
        }
        if (i < nchunk) chunk_off[i] = carry + sd[t] - v;
        __syncthreads();
        if (t == 0) carry += sd[255];
        __syncthreads();
    }
}

__global__ __launch_bounds__(256) void scan3_kernel(
    const int* __restrict__ cnt, const int* __restrict__ chunk_off,
    int* __restrict__ rowptr, int* __restrict__ fillptr,
    int* __restrict__ col, int* __restrict__ eid, int N)
{
    __shared__ int sd[256];
    int t = threadIdx.x;
    int n = blockIdx.x * 256 + t;
    int v = (n < N) ? (cnt[n] + 1) : 0;
    sd[t] = v;
    __syncthreads();
    for (int o = 1; o < 256; o <<= 1) {
        int x = (t >= o) ? sd[t - o] : 0;
        __syncthreads();
        sd[t] += x;
        __syncthreads();
    }
    if (n < N) {
        int incl = sd[t];
        int r = chunk_off[blockIdx.x] + incl - v;
        rowptr[n] = r;
        col[r] = n;        // self loop, first entry
        eid[r] = -1;
        fillptr[n] = r + 1;
        if (n == N - 1) rowptr[N] = chunk_off[blockIdx.x] + incl;
    }
}

__global__ __launch_bounds__(256) void fill_kernel(
    const int* __restrict__ src, const int* __restrict__ dst,
    int* __restrict__ fillptr, int* __restrict__ col, int* __restrict__ eid, int E)
{
    int e = blockIdx.x * 256 + threadIdx.x;
    if (e >= E) return;
    int d = dst[e];
    int p = atomicAdd(&fillptr[d], 1);
    col[p] = src[e];
    eid[p] = e;
}

// ====== edge_attr scatter-mean via CSR -> fp16 into Acat cols 128+ =========
// Acat row layout [N x 160] fp16: 0..127 nf, 128..143 nef_raw, 144..159 zero.
__global__ __launch_bounds__(256) void nef_csr_kernel(
    const float* __restrict__ ea, const int* __restrict__ rowptr,
    const int* __restrict__ eid,
    unsigned short* __restrict__ AF, int N)
{
    int n = blockIdx.x * 4 + (threadIdx.x >> 6);
    if (n >= N) return;
    int t = threadIdx.x & 63;
    int f = t & 15, g = t >> 4;
    int base = rowptr[n], end = rowptr[n + 1];
    int deg = end - base - 1;
    float acc = 0.0f;
    for (int j = base + 1 + g; j < end; j += 4) {
        int e = eid[j];
        acc += ea[(size_t)e * 16 + f];
    }
    acc += __shfl_down(acc, 32, 64);
    acc += __shfl_down(acc, 16, 64);
    if (t < 16) {
        float v = acc / fmaxf((float)deg, 1.0f);
        AF[(size_t)n * 160 + 128 + t] = f2h(v);
    } else if (t < 32) {
        AF[(size_t)n * 160 + 128 + t] = 0;
    }
}

// ====== convert node_feats f32 [N x 128] -> fp16 into Acat cols 0-127 ======
__global__ __launch_bounds__(256) void conv_f16_strided_kernel(
    const float* __restrict__ X, unsigned short* __restrict__ AF, int total)
{
    int base = (blockIdx.x * 256 + threadIdx.x) * 2;
    if (base >= total) return;
    #pragma unroll
    for (int i = 0; i < 2; i++) {
        int e = base + i;
        int row = e >> 7, c = e & 127;
        AF[(size_t)row * 160 + c] = f2h(X[e]);
    }
}

// ====== compose front-end weights (f32, exact):
// Wc rows 0..127 = Wnp @ Wg1[0:256,:], rows 128..143 = Wep @ Wg1[256:512,:],
// c1[j] = bnp @ Wg1[0:256,j] + bep @ Wg1[256:512,j].
__global__ __launch_bounds__(256) void compose_w1_kernel(
    const float* __restrict__ Wnp, const float* __restrict__ Wep,
    const float* __restrict__ bnp, const float* __restrict__ bep,
    const float* __restrict__ Wg1,
    float* __restrict__ Wc, float* __restrict__ c1)
{
    int idx = blockIdx.x * 256 + threadIdx.x;
    if (idx >= 145 * 256) return;
    int i = idx >> 8, j = idx & 255;
    float s = 0.0f;
    if (i < 128) {
        for (int k = 0; k < 256; k++) s += Wnp[i * 256 + k] * Wg1[(size_t)k * 256 + j];
        Wc[i * 256 + j] = s;
    } else if (i < 144) {
        int ii = i - 128;
        for (int k = 0; k < 256; k++) s += Wep[ii * 256 + k] * Wg1[(size_t)(256 + k) * 256 + j];
        Wc[i * 256 + j] = s;
    } else {
        for (int k = 0; k < 256; k++)
            s += bnp[k] * Wg1[(size_t)k * 256 + j] + bep[k] * Wg1[(size_t)(256 + k) * 256 + j];
        c1[j] = s;
    }
}

// ==== pack 3 weight matrices [K x 256] -> B-fragment order, fp16 hi/lo ====
__device__ __forceinline__ void pack_one(
    const float* __restrict__ W, int K, int KP, int idx,
    unsigned short* __restrict__ Ph, unsigned short* __restrict__ Pl)
{
    int tile = idx >> 9, w = idx & 511, lane = w >> 3, j = w & 7;
    int nk = KP >> 5;
    int ctile = tile / nk, t = tile % nk;
    int k = t * 32 + ((lane >> 4) << 3) + j;
    int n = (ctile << 4) + (lane & 15);
    float v = (k < K) ? W[(size_t)k * 256 + n] : 0.0f;
    unsigned short h, l;
    split_hilo16(v, h, l);
    Ph[idx] = h;
    Pl[idx] = l;
}

__global__ __launch_bounds__(256) void pack3_w_kernel(
    const float* __restrict__ Wc,  unsigned short* __restrict__ PcH,  unsigned short* __restrict__ PcL,
    const float* __restrict__ Wg2, unsigned short* __restrict__ Pg2H, unsigned short* __restrict__ Pg2L,
    const float* __restrict__ Wo,  unsigned short* __restrict__ PoH,  unsigned short* __restrict__ PoL)
{
    const int S0 = 160 * 256;            // Wc: K=144, KP=160
    const int S1 = S0 + 256 * 256;       // Wg2
    const int S2 = S1 + 256 * 256;       // Wo
    int idx = blockIdx.x * 256 + threadIdx.x;
    if (idx < S0) {
        pack_one(Wc, 144, 160, idx, PcH, PcL);
    } else if (idx < S1) {
        pack_one(Wg2, 256, 256, idx - S0, Pg2H, Pg2L);
    } else if (idx < S2) {
        pack_one(Wo, 256, 256, idx - S1, PoH, PoL);
    }
}

// ===================== MFMA fp16 GEMM ======================================
// C[N x 256] = A[N x KP] @ W[KP x 256] (+bias). Block: 64 rows x 128 cols
// (grid.y=2), 4 waves (wave = 16 rows), 8 col-tiles. B panel (fp16 hi/lo)
// double-buffered in LDS via global_load_lds; A register-prefetched one
// step ahead (static parity). AMODE: 0 = fp16 hilo A (3 MFMAs: ah*bh +
// al*bh + ah*bl), 1 = fp16 single A as DIRECT MFMA operand (2 MFMAs:
// a*bh + a*bl -- no VALU expansion). OMODE: 0 = f32, 1 = fp16 hilo,
// 2 = fp16 single. FUSE_ATT: per-row per-head dots of (acc+bias).
template <int KSTEPS, int AMODE, int OMODE, bool FUSE_ATT>
__global__ __launch_bounds__(256, 5) void mfma_gemm_kernel(
    const unsigned short* __restrict__ Ah, const unsigned short* __restrict__ Al,
    int lda,
    const unsigned short* __restrict__ Ph, const unsigned short* __restrict__ Pl,
    const float* __restrict__ bias,
    float* __restrict__ Cf,
    unsigned short* __restrict__ Ch, unsigned short* __restrict__ Cl,
    int ldc, int col_off, int Nrows,
    const float* __restrict__ att_src, const float* __restrict__ att_dst,
    float* __restrict__ a_srcO, float* __restrict__ a_dstO)
{
    __shared__ unsigned short ldsB[2][2][8][512];   // [buf][hi/lo][ctile][elem]
    int tid = threadIdx.x;
    int wave = tid >> 6, lane = tid & 63;
    int quad = lane >> 4, m16 = lane & 15;
    int rowblk = blockIdx.x, colhalf = blockIdx.y;
    int ctile0 = colhalf * 8;

    int row = rowblk * 64 + wave * 16 + m16;
    bool rowok = row < Nrows;
    const unsigned short* arh = Ah + (size_t)row * lda;
    const unsigned short* arl = (AMODE == 0) ? (Al + (size_t)row * lda) : nullptr;

    auto stage = [&](int t, int buf) {
        #pragma unroll
        for (int q = 0; q < 2; q++) {
            int c = wave * 2 + q;
            size_t gb = ((size_t)((ctile0 + c) * KSTEPS + t)) * 512 + lane * 8;
            gl2lds16(Ph + gb, &ldsB[buf][0][c][0]);
            gl2lds16(Pl + gb, &ldsB[buf][1][c][0]);
        }
    };
    auto loadA = [&](int t, f16x8& h, f16x8& l) {
        int k = t * 32 + quad * 8;
        h = (f16x8){};
        l = (f16x8){};
        if (rowok) {
            h = __builtin_bit_cast(f16x8, *(const u16x8*)(arh + k));
            if (AMODE == 0)
                l = __builtin_bit_cast(f16x8, *(const u16x8*)(arl + k));
        }
    };

    f32x4 acc[8] = {};
    f16x8 ah2[2], al2[2];
    loadA(0, ah2[0], al2[0]);
    stage(0, 0);
    __syncthreads();

    #pragma unroll
    for (int t = 0; t < KSTEPS; t++) {
        const int buf = t & 1;
        if (t + 1 < KSTEPS) {
            stage(t + 1, buf ^ 1);
            loadA(t + 1, ah2[(t + 1) & 1], al2[(t + 1) & 1]);   // static after unroll
        }
        #pragma unroll
        for (int c = 0; c < 8; c++) {
            f16x8 b_h = __builtin_bit_cast(f16x8, *(const u16x8*)&ldsB[buf][0][c][lane * 8]);
            f16x8 b_l = __builtin_bit_cast(f16x8, *(const u16x8*)&ldsB[buf][1][c][lane * 8]);
            acc[c] = __builtin_amdgcn_mfma_f32_16x16x32_f16(ah2[buf], b_h, acc[c], 0, 0, 0);
            if (AMODE == 0)
                acc[c] = __builtin_amdgcn_mfma_f32_16x16x32_f16(al2[buf], b_h, acc[c], 0, 0, 0);
            acc[c] = __builtin_amdgcn_mfma_f32_16x16x32_f16(ah2[buf], b_l, acc[c], 0, 0, 0);
        }
        if (t + 1 < KSTEPS) __syncthreads();
    }

    // epilogue: D[row = quad*4 + r][col = m16] within each 16x16 tile
    #pragma unroll
    for (int c = 0; c < 8; c++) {
        int ocol = (ctile0 + c) * 16 + m16;
        float bv = bias ? bias[ocol] : 0.0f;
        #pragma unroll
        for (int r = 0; r < 4; r++) {
            int orow = rowblk * 64 + wave * 16 + quad * 4 + r;
            if (orow >= Nrows) continue;
            float v = acc[c][r] + bv;
            size_t oidx = (size_t)orow * ldc + col_off + ocol;
            if (OMODE == 1) {
                unsigned short h, l;
                split_hilo16(v, h, l);
                Ch[oidx] = h;
                Cl[oidx] = l;
            } else if (OMODE == 2) {
                Ch[oidx] = f2h(v);
            } else {
                Cf[oidx] = v;
            }
        }
    }

    if (FUSE_ATT) {
        float ps[4][2] = {}, pd[4][2] = {};
        #pragma unroll
        for (int c = 0; c < 8; c++) {
            int ocol = (ctile0 + c) * 16 + m16;
            float bv = bias ? bias[ocol] : 0.0f;
            float asv = att_src[ocol];
            float adv = att_dst[ocol];
            int hl = c >> 2;
            #pragma unroll
            for (int r = 0; r < 4; r++) {
                float v = acc[c][r] + bv;
                ps[r][hl] += v * asv;
                pd[r][hl] += v * adv;
            }
        }
        #pragma unroll
        for (int r = 0; r < 4; r++) {
            #pragma unroll
            for (int hl = 0; hl < 2; hl++) {
                float s = ps[r][hl], d = pd[r][hl];
                #pragma unroll
                for (int o = 8; o > 0; o >>= 1) {
                    s += __shfl_down(s, o, 64);
                    d += __shfl_down(d, o, 64);
                }
                if (m16 == 0) {
                    int orow = rowblk * 64 + wave * 16 + quad * 4 + r;
                    if (orow < Nrows) {
                        int gh = colhalf * 2 + hl;
                        a_srcO[orow * 4 + gh] = s;
                        a_dstO[orow * 4 + gh] = d;
                    }
                }
            }
        }
    }
}

// ===== CSR aggregation: wave-per-node; fused weight phase + weighted sum ===
// 4 nodes per 256-thread block; wave w owns node blockIdx*4+w.
// Phase 1 (fast path, deg<=128): lane-per-edge computes all 4 head weights
// into wave-private LDS + shuffle-reduced denominator (producer wave ==
// consumer wave, no barrier). Slow path (deg>128, ~never): inline weights.
// Phase 2: each lane covers 4 consecutive cols; masked unroll-4 gather.
// OUTF16: true -> single fp16 store (x3); false -> fp16 hilo (x4).
template <bool OUTF16>
__global__ __launch_bounds__(256) void gat_agg_csr_kernel(
    const unsigned short* __restrict__ xh,      // fp16 [N x 256]
    const int* __restrict__ rowptr, const int* __restrict__ col,
    const float* __restrict__ a_src, const float* __restrict__ a_dst,
    const float* __restrict__ bias,
    unsigned short* __restrict__ outA, unsigned short* __restrict__ outB, int N)
{
    __shared__ float wlds[4][128][HEADS];       // 8 KB, wave-private rows
    int t = threadIdx.x;
    int wv = t >> 6;
    int n = blockIdx.x * 4 + wv;
    if (n >= N) return;
    int c = t & 63;
    int h = c >> 4;
    int base = rowptr[n], end = rowptr[n + 1];
    int deg = end - base;                       // >= 1 (self loop)
    int e1 = end - 1;
    float4 ad = *(const float4*)&a_dst[n * 4];
    float adh = (h == 0) ? ad.x : (h == 1) ? ad.y : (h == 2) ? ad.z : ad.w;
    const unsigned short* xcol = xh + (c << 2);

    float4 acc = {0.0f, 0.0f, 0.0f, 0.0f};
    float den = 0.0f;

    if (deg <= 128) {
        // ---- phase 1: weights into LDS (lane-per-edge) + denominator ----
        float4 ds = {0.0f, 0.0f, 0.0f, 0.0f};
        for (int j = base + c; j < end; j += 64) {
            int s = col[j];
            float4 as4 = *(const float4*)&a_src[s * 4];
            float l0 = as4.x + ad.x, l1 = as4.y + ad.y;
            float l2 = as4.z + ad.z, l3 = as4.w + ad.w;
            l0 = fmaxf(l0, 0.2f * l0);
            l1 = fmaxf(l1, 0.2f * l1);
            l2 = fmaxf(l2, 0.2f * l2);
            l3 = fmaxf(l3, 0.2f * l3);
            float4 wv4 = {__expf(l0), __expf(l1), __expf(l2), __expf(l3)};
            *(float4*)&wlds[wv][j - base][0] = wv4;
            ds.x += wv4.x; ds.y += wv4.y; ds.z += wv4.z; ds.w += wv4.w;
        }
        #pragma unroll
        for (int o = 32; o > 0; o >>= 1) {
            ds.x += __shfl_down(ds.x, o, 64);
            ds.y += __shfl_down(ds.y, o, 64);
            ds.z += __shfl_down(ds.z, o, 64);
            ds.w += __shfl_down(ds.w, o, 64);
        }
        float d0 = __shfl(ds.x, 0, 64);
        float d1 = __shfl(ds.y, 0, 64);
        float d2 = __shfl(ds.z, 0, 64);
        float d3 = __shfl(ds.w, 0, 64);
        den = (h == 0) ? d0 : (h == 1) ? d1 : (h == 2) ? d2 : d3;

        // ---- phase 2: gather-accumulate, weights broadcast from LDS ----
        for (int j = base; j < end; j += 4) {
            int j1 = j + 1 < e1 ? j + 1 : e1;
            int j2 = j + 2 < e1 ? j + 2 : e1;
            int j3 = j + 3 < e1 ? j + 3 : e1;
            int s0 = col[j], s1 = col[j1], s2 = col[j2], s3 = col[j3];
            float w0 = wlds[wv][j - base][h];
            float w1 = (j + 1 < end) ? wlds[wv][j1 - base][h] : 0.0f;
            float w2 = (j + 2 < end) ? wlds[wv][j2 - base][h] : 0.0f;
            float w3 = (j + 3 < end) ? wlds[wv][j3 - base][h] : 0.0f;
            u16x4 x0 = *(const u16x4*)(xcol + (size_t)s0 * 256);
            u16x4 x1 = *(const u16x4*)(xcol + (size_t)s1 * 256);
            u16x4 x2 = *(const u16x4*)(xcol + (size_t)s2 * 256);
            u16x4 x3 = *(const u16x4*)(xcol + (size_t)s3 * 256);
            acc.x += w0 * h2f(x0[0]) + w1 * h2f(x1[0]) + w2 * h2f(x2[0]) + w3 * h2f(x3[0]);
            acc.y += w0 * h2f(x0[1]) + w1 * h2f(x1[1]) + w2 * h2f(x2[1]) + w3 * h2f(x3[1]);
            acc.z += w0 * h2f(x0[2]) + w1 * h2f(x1[2]) + w2 * h2f(x2[2]) + w3 * h2f(x3[2]);
            acc.w += w0 * h2f(x0[3]) + w1 * h2f(x1[3]) + w2 * h2f(x2[3]) + w3 * h2f(x3[3]);
        }
    } else {
        // ---- slow path (deg > 128, practically never): inline weights ----
        for (int j = base; j < end; j += 4) {
            int j1 = j + 1 < e1 ? j + 1 : e1;
            int j2 = j + 2 < e1 ? j + 2 : e1;
            int j3 = j + 3 < e1 ? j + 3 : e1;
            int s0 = col[j], s1 = col[j1], s2 = col[j2], s3 = col[j3];
            float l0 = a_src[s0 * 4 + h] + adh;
            float l1 = a_src[s1 * 4 + h] + adh;
            float l2 = a_src[s2 * 4 + h] + adh;
            float l3 = a_src[s3 * 4 + h] + adh;
            l0 = fmaxf(l0, 0.2f * l0);
            l1 = fmaxf(l1, 0.2f * l1);
            l2 = fmaxf(l2, 0.2f * l2);
            l3 = fmaxf(l3, 0.2f * l3);
            float w0 = __expf(l0);
            float w1 = (j + 1 < end) ? __expf(l1) : 0.0f;
            float w2 = (j + 2 < end) ? __expf(l2) : 0.0f;
            float w3 = (j + 3 < end) ? __expf(l3) : 0.0f;
            u16x4 x0 = *(const u16x4*)(xcol + (size_t)s0 * 256);
            u16x4 x1 = *(const u16x4*)(xcol + (size_t)s1 * 256);
            u16x4 x2 = *(const u16x4*)(xcol + (size_t)s2 * 256);
            u16x4 x3 = *(const u16x4*)(xcol + (size_t)s3 * 256);
            den += (w0 + w1) + (w2 + w3);
            acc.x += w0 * h2f(x0[0]) + w1 * h2f(x1[0]) + w2 * h2f(x2[0]) + w3 * h2f(x3[0]);
            acc.y += w0 * h2f(x0[1]) + w1 * h2f(x1[1]) + w2 * h2f(x2[1]) + w3 * h2f(x3[1]);
            acc.z += w0 * h2f(x0[2]) + w1 * h2f(x1[2]) + w2 * h2f(x2[2]) + w3 * h2f(x3[2]);
            acc.w += w0 * h2f(x0[3]) + w1 * h2f(x1[3]) + w2 * h2f(x2[3]) + w3 * h2f(x3[3]);
        }
    }

    float inv = 1.0f / den;
    float4 bv = *(const float4*)(bias + (c << 2));
    float o0 = acc.x * inv + bv.x;
    float o1 = acc.y * inv + bv.y;
    float o2 = acc.z * inv + bv.z;
    float o3 = acc.w * inv + bv.w;
    o0 = (o0 > 0.0f) ? o0 : (__expf(o0) - 1.0f);
    o1 = (o1 > 0.0f) ? o1 : (__expf(o1) - 1.0f);
    o2 = (o2 > 0.0f) ? o2 : (__expf(o2) - 1.0f);
    o3 = (o3 > 0.0f) ? o3 : (__expf(o3) - 1.0f);
    if (OUTF16) {
        u16x4 H;
        H[0] = f2h(o0); H[1] = f2h(o1); H[2] = f2h(o2); H[3] = f2h(o3);
        *(u16x4*)(&outA[(size_t)n * 256 + (c << 2)]) = H;
    } else {
        u16x4 H, L;
        split_hilo16(o0, ((unsigned short*)&H)[0], ((unsigned short*)&L)[0]);
        split_hilo16(o1, ((unsigned short*)&H)[1], ((unsigned short*)&L)[1]);
        split_hilo16(o2, ((unsigned short*)&H)[2], ((unsigned short*)&L)[2]);
        split_hilo16(o3, ((unsigned short*)&H)[3], ((unsigned short*)&L)[3]);
        *(u16x4*)(&outA[(size_t)n * 256 + (c << 2)]) = H;
        *(u16x4*)(&outB[(size_t)n * 256 + (c << 2)]) = L;
    }
}

// ===========================================================================

extern "C" void kernel_launch(void* const* d_in, const int* in_sizes, int n_in,
                              void* d_out, int out_size, void* d_ws, size_t ws_size,
                              hipStream_t stream)
{
    const float* node_feats = (const float*)d_in[0];
    const float* edge_attr  = (const float*)d_in[1];
    const float* Wnp = (const float*)d_in[2];
    const float* bnp = (const float*)d_in[3];
    const float* Wep = (const float*)d_in[4];
    const float* bep = (const float*)d_in[5];
    const float* Wg1 = (const float*)d_in[6];
    const float* as1 = (const float*)d_in[7];
    const float* ad1 = (const float*)d_in[8];
    const float* bg1 = (const float*)d_in[9];
    const float* Wg2 = (const float*)d_in[10];
    const float* as2 = (const float*)d_in[11];
    const float* ad2 = (const float*)d_in[12];
    const float* bg2 = (const float*)d_in[13];
    const float* Wo  = (const float*)d_in[14];
    const float* bo  = (const float*)d_in[15];
    const int*   ei  = (const int*)d_in[16];

    const int N = in_sizes[0] / 128;   // 50000
    const int E = in_sizes[16] / 2;    // 800000
    const int* src = ei;
    const int* dst = ei + E;
    const int nchunk = (N + 255) / 256;
    const int EN = E + N;

    typedef unsigned short u16;

    // ---- workspace layout (256B-aligned regions) ----
    char* base = (char*)d_ws;
    size_t off = 0;
    auto alloc = [&](size_t bytes) -> char* {
        char* p = base + off;
        off += (bytes + 255) & ~(size_t)255;
        return p;
    };
    u16* xhh = (u16*)alloc((size_t)N * 256 * 2);           // fp16 xh [N x 256]
    u16* R2  = (u16*)alloc((size_t)N * 512 * 2);           // AcatF then x3F
    u16* R3  = (u16*)alloc((size_t)N * 512 * 2);           // x4H/x4L (fp16 hilo)
    float* a_src = (float*)alloc((size_t)N * 4 * 4);
    float* a_dst = (float*)alloc((size_t)N * 4 * 4);
    float* Wc    = (float*)alloc(144 * 256 * 4);           // composed front weights
    float* c1    = (float*)alloc(256 * 4);                 // composed front bias
    u16* PcH  = (u16*)alloc(160 * 256 * 2);
    u16* PcL  = (u16*)alloc(160 * 256 * 2);
    u16* Pg2H = (u16*)alloc(256 * 256 * 2);
    u16* Pg2L = (u16*)alloc(256 * 256 * 2);
    u16* PoH  = (u16*)alloc(256 * 256 * 2);
    u16* PoL  = (u16*)alloc(256 * 256 * 2);
    int* cnt       = (int*)alloc((size_t)N * 4);
    int* rowptr    = (int*)alloc((size_t)(N + 1) * 4);
    int* fillptr   = (int*)alloc((size_t)N * 4);
    int* chunk_sum = (int*)alloc((size_t)nchunk * 4);
    int* chunk_off = (int*)alloc((size_t)nchunk * 4);
    int* colv      = (int*)alloc((size_t)EN * 4);
    int* eid       = (int*)alloc((size_t)EN * 4);

    // AcatF [N x 160] fp16 lives in R2 until GAT1 GEMM completes; x3F
    // (agg1 out, [N x 256] fp16) reuses R2 afterwards. x4 fp16-hilo in R3.
    u16* AcatF = R2;
    u16* x3F   = R2;
    u16* x4H = R3;
    u16* x4L = R3 + (size_t)N * 256;

    float* out = (float*)d_out;
    dim3 ggrid((N + 63) / 64, 2);

    // ---- CSR build ----
    hipMemsetAsync(cnt, 0, (size_t)N * sizeof(int), stream);
    count_kernel<<<(E + 255) / 256, 256, 0, stream>>>(dst, cnt, E);
    scan1_kernel<<<nchunk, 256, 0, stream>>>(cnt, chunk_sum, N);
    scan2_kernel<<<1, 256, 0, stream>>>(chunk_sum, chunk_off, nchunk);
    scan3_kernel<<<nchunk, 256, 0, stream>>>(cnt, chunk_off, rowptr, fillptr, colv, eid, N);
    fill_kernel<<<(E + 255) / 256, 256, 0, stream>>>(src, dst, fillptr, colv, eid, E);

    // ---- inputs -> Acat (fp16); weight compose + packing ----
    nef_csr_kernel<<<(N + 3) / 4, 256, 0, stream>>>(edge_attr, rowptr, eid, AcatF, N);
    conv_f16_strided_kernel<<<((N * 128) / 2 + 255) / 256, 256, 0, stream>>>(
        node_feats, AcatF, N * 128);
    compose_w1_kernel<<<145, 256, 0, stream>>>(Wnp, Wep, bnp, bep, Wg1, Wc, c1);
    {
        const int total = 160 * 256 + 256 * 256 + 256 * 256;
        pack3_w_kernel<<<(total + 255) / 256, 256, 0, stream>>>(
            Wc, PcH, PcL, Wg2, Pg2H, Pg2L, Wo, PoH, PoL);
    }

    // ---- GAT layer 1: composed GEMM (K=160, fp16 A single) -> agg ----
    mfma_gemm_kernel<5, 1, 2, true><<<ggrid, 256, 0, stream>>>(
        AcatF, nullptr, 160, PcH, PcL, c1, nullptr, xhh, nullptr, 256, 0, N,
        as1, ad1, a_src, a_dst);
    gat_agg_csr_kernel<true><<<(N + 3) / 4, 256, 0, stream>>>(
        xhh, rowptr, colv, a_src, a_dst, bg1, x3F, nullptr, N);

    // ---- GAT layer 2 (fp16 A single) ----
    mfma_gemm_kernel<8, 1, 2, true><<<ggrid, 256, 0, stream>>>(
        x3F, nullptr, 256, Pg2H, Pg2L, nullptr, nullptr, xhh, nullptr, 256, 0, N,
        as2, ad2, a_src, a_dst);
    gat_agg_csr_kernel<false><<<(N + 3) / 4, 256, 0, stream>>>(
        xhh, rowptr, colv, a_src, a_dst, bg2, x4H, x4L, N);

    // ---- out = x4 @ Wo + bo -> d_out (f32), fp16 hilo A ----
    mfma_gemm_kernel<8, 0, 0, false><<<ggrid, 256, 0, stream>>>(
        x4H, x4L, 256, PoH, PoL, bo, out, nullptr, nullptr, 256, 0, N,
        nullptr, nullptr, nullptr, nullptr);
}

// Round 9
// 532.156 us; speedup vs baseline: 1.3021x; 1.0129x over previous
//
#include <hip/hip_runtime.h>
#include <hip/hip_bf16.h>

// GNN: node_proj + edge scatter_mean/proj -> concat -> GAT(512->4x64) -> ELU
//      -> GAT(256->4x64) -> ELU -> out_proj. ALL tensors float32 (per ref).
// R15: (1) GEMM: preload ALL A fragments at kernel entry (<=16 loads, all
//      independent & in flight). The per-kstep __syncthreads vmcnt(0) then
//      pays A latency ONCE (first barrier) instead of every k-step -- this
//      is why R10/R12's one-step-ahead prefetch never helped (each barrier
//      re-drained it). launch_bounds(256,4) for the VGPR headroom.
//      (2) conv kernel deleted: GEMM1 reads node_feats f32 directly
//      (ksteps 0-3, cvt in-register == stored fp16 bit-identical) + compact
//      nef fp16 [N x 32] (kstep 4). Saves 41.6MB round-trip + a dispatch.
//      Agg untouched: pegged at ~3.0 TB/s fabric gather ceiling
//      (R7/R8/R11/R12/R13: 210MB @ ~71us x2).

#define HEADS 4

typedef __attribute__((ext_vector_type(8))) _Float16 f16x8;
typedef __attribute__((ext_vector_type(4))) float f32x4;
typedef __attribute__((ext_vector_type(4))) unsigned short u16x4;
typedef __attribute__((ext_vector_type(8))) unsigned short u16x8;

__device__ __forceinline__ unsigned short f2h(float v) {
    _Float16 h = (_Float16)v;                 // v_cvt_f16_f32, RN
    return __builtin_bit_cast(unsigned short, h);
}
__device__ __forceinline__ float h2f(unsigned short u) {
    return (float)__builtin_bit_cast(_Float16, u);
}
// fp16 hi/lo split: h + l reproduces v to ~22 mantissa bits
__device__ __forceinline__ void split_hilo16(float v, unsigned short& h, unsigned short& l) {
    h = f2h(v);
    l = f2h(v - h2f(h));
}
// async global->LDS, 16B per lane; LDS dest is wave-uniform base + lane*16
__device__ __forceinline__ void gl2lds16(const unsigned short* g, unsigned short* l) {
    __builtin_amdgcn_global_load_lds(
        (const __attribute__((address_space(1))) unsigned int*)g,
        (__attribute__((address_space(3))) unsigned int*)l,
        16, 0, 0);
}

// ============================ CSR construction =============================

__global__ __launch_bounds__(256) void count_kernel(
    const int* __restrict__ dst, int* __restrict__ cnt, int E)
{
    int e = blockIdx.x * 256 + threadIdx.x;
    if (e < E) atomicAdd(&cnt[dst[e]], 1);
}

__global__ __launch_bounds__(256) void scan1_kernel(
    const int* __restrict__ cnt, int* __restrict__ chunk_sum, int N)
{
    __shared__ int sd[256];
    int t = threadIdx.x;
    int n = blockIdx.x * 256 + t;
    sd[t] = (n < N) ? (cnt[n] + 1) : 0;
    __syncthreads();
    for (int o = 128; o > 0; o >>= 1) {
        if (t < o) sd[t] += sd[t + o];
        __syncthreads();
    }
    if (t == 0) chunk_sum[blockIdx.x] = sd[0];
}

// 1-block 256-thread scan over chunk sums
__global__ __launch_bounds__(256) void scan2_kernel(
    const int* __restrict__ chunk_sum, int* __restrict__ chunk_off, int nchunk)
{
    __shared__ int sd[256];
    __shared__ int carry;
    int t = threadIdx.x;
    if (t == 0) carry = 0;
    __syncthreads();
    for (int b = 0; b < nchunk; b += 256) {
        int i = b + t;
        int v = (i < nchunk) ? chunk_sum[i] : 0;
        sd[t] = v;
        __syncthreads();
        for (int o = 1; o < 256; o <<= 1) {
            int x = (t >= o) ? sd[t - o] : 0;
            __syncthreads();
            sd[t] += x;
            __syncthreads();
        }
        if (i < nchunk) chunk_off[i] = carry + sd[t] - v;
        __syncthreads();
        if (t == 0) carry += sd[255];
        __syncthreads();
    }
}

__global__ __launch_bounds__(256) void scan3_kernel(
    const int* __restrict__ cnt, const int* __restrict__ chunk_off,
    int* __restrict__ rowptr, int* __restrict__ fillptr,
    int* __restrict__ col, int* __restrict__ eid, int N)
{
    __shared__ int sd[256];
    int t = threadIdx.x;
    int n = blockIdx.x * 256 + t;
    int v = (n < N) ? (cnt[n] + 1) : 0;
    sd[t] = v;
    __syncthreads();
    for (int o = 1; o < 256; o <<= 1) {
        int x = (t >= o) ? sd[t - o] : 0;
        __syncthreads();
        sd[t] += x;
        __syncthreads();
    }
    if (n < N) {
        int incl = sd[t];
        int r = chunk_off[blockIdx.x] + incl - v;
        rowptr[n] = r;
        col[r] = n;        // self loop, first entry
        eid[r] = -1;
        fillptr[n] = r + 1;
        if (n == N - 1) rowptr[N] = chunk_off[blockIdx.x] + incl;
    }
}

__global__ __launch_bounds__(256) void fill_kernel(
    const int* __restrict__ src, const int* __restrict__ dst,
    int* __restrict__ fillptr, int* __restrict__ col, int* __restrict__ eid, int E)
{
    int e = blockIdx.x * 256 + threadIdx.x;
    if (e >= E) return;
    int d = dst[e];
    int p = atomicAdd(&fillptr[d], 1);
    col[p] = src[e];
    eid[p] = e;
}

// ====== edge_attr scatter-mean via CSR -> compact fp16 nef [N x 32] ========
// cols 0..15 = mean(edge_attr), 16..31 = zero (K padding for the GEMM).
__global__ __launch_bounds__(256) void nef_csr_kernel(
    const float* __restrict__ ea, const int* __restrict__ rowptr,
    const int* __restrict__ eid,
    unsigned short* __restrict__ nefF, int N)
{
    int n = blockIdx.x * 4 + (threadIdx.x >> 6);
    if (n >= N) return;
    int t = threadIdx.x & 63;
    int f = t & 15, g = t >> 4;
    int base = rowptr[n], end = rowptr[n + 1];
    int deg = end - base - 1;
    float acc = 0.0f;
    for (int j = base + 1 + g; j < end; j += 4) {
        int e = eid[j];
        acc += ea[(size_t)e * 16 + f];
    }
    acc += __shfl_down(acc, 32, 64);
    acc += __shfl_down(acc, 16, 64);
    if (t < 16) {
        float v = acc / fmaxf((float)deg, 1.0f);
        nefF[(size_t)n * 32 + t] = f2h(v);
    } else if (t < 32) {
        nefF[(size_t)n * 32 + t] = 0;
    }
}

// ====== compose front-end weights (f32, exact):
// Wc rows 0..127 = Wnp @ Wg1[0:256,:], rows 128..143 = Wep @ Wg1[256:512,:],
// c1[j] = bnp @ Wg1[0:256,j] + bep @ Wg1[256:512,j].
__global__ __launch_bounds__(256) void compose_w1_kernel(
    const float* __restrict__ Wnp, const float* __restrict__ Wep,
    const float* __restrict__ bnp, const float* __restrict__ bep,
    const float* __restrict__ Wg1,
    float* __restrict__ Wc, float* __restrict__ c1)
{
    int idx = blockIdx.x * 256 + threadIdx.x;
    if (idx >= 145 * 256) return;
    int i = idx >> 8, j = idx & 255;
    float s = 0.0f;
    if (i < 128) {
        for (int k = 0; k < 256; k++) s += Wnp[i * 256 + k] * Wg1[(size_t)k * 256 + j];
        Wc[i * 256 + j] = s;
    } else if (i < 144) {
        int ii = i - 128;
        for (int k = 0; k < 256; k++) s += Wep[ii * 256 + k] * Wg1[(size_t)(256 + k) * 256 + j];
        Wc[i * 256 + j] = s;
    } else {
        for (int k = 0; k < 256; k++)
            s += bnp[k] * Wg1[(size_t)k * 256 + j] + bep[k] * Wg1[(size_t)(256 + k) * 256 + j];
        c1[j] = s;
    }
}

// ==== pack 3 weight matrices [K x 256] -> B-fragment order, fp16 hi/lo ====
__device__ __forceinline__ void pack_one(
    const float* __restrict__ W, int K, int KP, int idx,
    unsigned short* __restrict__ Ph, unsigned short* __restrict__ Pl)
{
    int tile = idx >> 9, w = idx & 511, lane = w >> 3, j = w & 7;
    int nk = KP >> 5;
    int ctile = tile / nk, t = tile % nk;
    int k = t * 32 + ((lane >> 4) << 3) + j;
    int n = (ctile << 4) + (lane & 15);
    float v = (k < K) ? W[(size_t)k * 256 + n] : 0.0f;
    unsigned short h, l;
    split_hilo16(v, h, l);
    Ph[idx] = h;
    Pl[idx] = l;
}

__global__ __launch_bounds__(256) void pack3_w_kernel(
    const float* __restrict__ Wc,  unsigned short* __restrict__ PcH,  unsigned short* __restrict__ PcL,
    const float* __restrict__ Wg2, unsigned short* __restrict__ Pg2H, unsigned short* __restrict__ Pg2L,
    const float* __restrict__ Wo,  unsigned short* __restrict__ PoH,  unsigned short* __restrict__ PoL)
{
    const int S0 = 160 * 256;            // Wc: K=144, KP=160
    const int S1 = S0 + 256 * 256;       // Wg2
    const int S2 = S1 + 256 * 256;       // Wo
    int idx = blockIdx.x * 256 + threadIdx.x;
    if (idx < S0) {
        pack_one(Wc, 144, 160, idx, PcH, PcL);
    } else if (idx < S1) {
        pack_one(Wg2, 256, 256, idx - S0, Pg2H, Pg2L);
    } else if (idx < S2) {
        pack_one(Wo, 256, 256, idx - S1, PoH, PoL);
    }
}

// ===================== MFMA fp16 GEMM ======================================
// C[N x 256] = A[N x KP] @ W[KP x 256] (+bias). Block: 64 rows x 128 cols
// (grid.y=2), 4 waves (wave = 16 rows), 8 col-tiles. B panel (fp16 hi/lo)
// double-buffered in LDS via global_load_lds. ALL A fragments preloaded at
// kernel entry (independent, all in flight; first barrier pays latency once,
// later barriers have zero A exposure). AMODE: 0 = fp16 hilo A (3 MFMAs),
// 1 = fp16 single A (2 MFMAs), 3 = GEMM1-direct: ksteps 0..KSTEPS-2 read
// f32 from Af32 [N x 128] (cvt in-register, bit-identical to stored fp16),
// last kstep reads compact nef fp16 [N x 32]. OMODE: 0 = f32, 1 = fp16
// hilo, 2 = fp16. FUSE_ATT: per-row per-head dots of (acc+bias).
template <int KSTEPS, int AMODE, int OMODE, bool FUSE_ATT>
__global__ __launch_bounds__(256, 4) void mfma_gemm_kernel(
    const unsigned short* __restrict__ Ah, const unsigned short* __restrict__ Al,
    const float* __restrict__ Af32,
    int lda,
    const unsigned short* __restrict__ Ph, const unsigned short* __restrict__ Pl,
    const float* __restrict__ bias,
    float* __restrict__ Cf,
    unsigned short* __restrict__ Ch, unsigned short* __restrict__ Cl,
    int ldc, int col_off, int Nrows,
    const float* __restrict__ att_src, const float* __restrict__ att_dst,
    float* __restrict__ a_srcO, float* __restrict__ a_dstO)
{
    __shared__ unsigned short ldsB[2][2][8][512];   // [buf][hi/lo][ctile][elem]
    int tid = threadIdx.x;
    int wave = tid >> 6, lane = tid & 63;
    int quad = lane >> 4, m16 = lane & 15;
    int rowblk = blockIdx.x, colhalf = blockIdx.y;
    int ctile0 = colhalf * 8;

    int row = rowblk * 64 + wave * 16 + m16;
    bool rowok = row < Nrows;

    auto stage = [&](int t, int buf) {
        #pragma unroll
        for (int q = 0; q < 2; q++) {
            int c = wave * 2 + q;
            size_t gb = ((size_t)((ctile0 + c) * KSTEPS + t)) * 512 + lane * 8;
            gl2lds16(Ph + gb, &ldsB[buf][0][c][0]);
            gl2lds16(Pl + gb, &ldsB[buf][1][c][0]);
        }
    };

    // ---------- preload ALL A fragments (independent, all in flight) ------
    u16x8 aH[KSTEPS];                       // fp16 frags (AMODE 0/1; AMODE3: last)
    u16x8 aL[AMODE == 0 ? KSTEPS : 1];      // lo frags (AMODE 0 only)
    f32x4 aF[AMODE == 3 ? 2 * KSTEPS : 1];  // f32 pairs (AMODE 3, ksteps 0..KS-2)
    #pragma unroll
    for (int t = 0; t < KSTEPS; t++) {
        if (AMODE == 3) {
            if (t < KSTEPS - 1) {
                aF[2 * t] = (f32x4){};
                aF[2 * t + 1] = (f32x4){};
                if (rowok) {
                    const float* p = Af32 + (size_t)row * 128 + t * 32 + quad * 8;
                    aF[2 * t]     = *(const f32x4*)p;
                    aF[2 * t + 1] = *(const f32x4*)(p + 4);
                }
            } else {
                aH[t] = (u16x8){};
                if (rowok) aH[t] = *(const u16x8*)(Ah + (size_t)row * 32 + quad * 8);
            }
        } else {
            int k = t * 32 + quad * 8;
            aH[t] = (u16x8){};
            if (rowok) aH[t] = *(const u16x8*)(Ah + (size_t)row * lda + k);
            if (AMODE == 0) {
                aL[t] = (u16x8){};
                if (rowok) aL[t] = *(const u16x8*)(Al + (size_t)row * lda + k);
            }
        }
    }

    f32x4 acc[8] = {};
    stage(0, 0);
    __syncthreads();

    #pragma unroll
    for (int t = 0; t < KSTEPS; t++) {
        const int buf = t & 1;
        if (t + 1 < KSTEPS) stage(t + 1, buf ^ 1);

        // materialize this step's fp16 A operand (static index after unroll)
        f16x8 a_h, a_l;
        if (AMODE == 3 && t < KSTEPS - 1) {
            #pragma unroll
            for (int i = 0; i < 4; i++) {
                ((_Float16*)&a_h)[i]     = (_Float16)aF[2 * t][i];
                ((_Float16*)&a_h)[4 + i] = (_Float16)aF[2 * t + 1][i];
            }
        } else {
            a_h = __builtin_bit_cast(f16x8, aH[t]);
        }
        if (AMODE == 0) a_l = __builtin_bit_cast(f16x8, aL[t]);

        #pragma unroll
        for (int c = 0; c < 8; c++) {
            f16x8 b_h = __builtin_bit_cast(f16x8, *(const u16x8*)&ldsB[buf][0][c][lane * 8]);
            f16x8 b_l = __builtin_bit_cast(f16x8, *(const u16x8*)&ldsB[buf][1][c][lane * 8]);
            acc[c] = __builtin_amdgcn_mfma_f32_16x16x32_f16(a_h, b_h, acc[c], 0, 0, 0);
            if (AMODE == 0)
                acc[c] = __builtin_amdgcn_mfma_f32_16x16x32_f16(a_l, b_h, acc[c], 0, 0, 0);
            acc[c] = __builtin_amdgcn_mfma_f32_16x16x32_f16(a_h, b_l, acc[c], 0, 0, 0);
        }
        if (t + 1 < KSTEPS) __syncthreads();
    }

    // epilogue: D[row = quad*4 + r][col = m16] within each 16x16 tile
    #pragma unroll
    for (int c = 0; c < 8; c++) {
        int ocol = (ctile0 + c) * 16 + m16;
        float bv = bias ? bias[ocol] : 0.0f;
        #pragma unroll
        for (int r = 0; r < 4; r++) {
            int orow = rowblk * 64 + wave * 16 + quad * 4 + r;
            if (orow >= Nrows) continue;
            float v = acc[c][r] + bv;
            size_t oidx = (size_t)orow * ldc + col_off + ocol;
            if (OMODE == 1) {
                unsigned short h, l;
                split_hilo16(v, h, l);
                Ch[oidx] = h;
                Cl[oidx] = l;
            } else if (OMODE == 2) {
                Ch[oidx] = f2h(v);
            } else {
                Cf[oidx] = v;
            }
        }
    }

    if (FUSE_ATT) {
        float ps[4][2] = {}, pd[4][2] = {};
        #pragma unroll
        for (int c = 0; c < 8; c++) {
            int ocol = (ctile0 + c) * 16 + m16;
            float bv = bias ? bias[ocol] : 0.0f;
            float asv = att_src[ocol];
            float adv = att_dst[ocol];
            int hl = c >> 2;
            #pragma unroll
            for (int r = 0; r < 4; r++) {
                float v = acc[c][r] + bv;
                ps[r][hl] += v * asv;
                pd[r][hl] += v * adv;
            }
        }
        #pragma unroll
        for (int r = 0; r < 4; r++) {
            #pragma unroll
            for (int hl = 0; hl < 2; hl++) {
                float s = ps[r][hl], d = pd[r][hl];
                #pragma unroll
                for (int o = 8; o > 0; o >>= 1) {
                    s += __shfl_down(s, o, 64);
                    d += __shfl_down(d, o, 64);
                }
                if (m16 == 0) {
                    int orow = rowblk * 64 + wave * 16 + quad * 4 + r;
                    if (orow < Nrows) {
                        int gh = colhalf * 2 + hl;
                        a_srcO[orow * 4 + gh] = s;
                        a_dstO[orow * 4 + gh] = d;
                    }
                }
            }
        }
    }
}

// ===== CSR aggregation: wave-per-node; fused weight phase + weighted sum ===
// 4 nodes per 256-thread block; wave w owns node blockIdx*4+w.
// Phase 1 (fast path, deg<=128): lane-per-edge computes all 4 head weights
// into wave-private LDS + shuffle-reduced denominator (producer wave ==
// consumer wave, no barrier). Slow path (deg>128, ~never): inline weights.
// Phase 2: each lane covers 4 consecutive cols; masked unroll-4 gather.
// OUTF16: true -> single fp16 store (x3); false -> fp16 hilo (x4).
template <bool OUTF16>
__global__ __launch_bounds__(256) void gat_agg_csr_kernel(
    const unsigned short* __restrict__ xh,      // fp16 [N x 256]
    const int* __restrict__ rowptr, const int* __restrict__ col,
    const float* __restrict__ a_src, const float* __restrict__ a_dst,
    const float* __restrict__ bias,
    unsigned short* __restrict__ outA, unsigned short* __restrict__ outB, int N)
{
    __shared__ float wlds[4][128][HEADS];       // 8 KB, wave-private rows
    int t = threadIdx.x;
    int wv = t >> 6;
    int n = blockIdx.x * 4 + wv;
    if (n >= N) return;
    int c = t & 63;
    int h = c >> 4;
    int base = rowptr[n], end = rowptr[n + 1];
    int deg = end - base;                       // >= 1 (self loop)
    int e1 = end - 1;
    float4 ad = *(const float4*)&a_dst[n * 4];
    float adh = (h == 0) ? ad.x : (h == 1) ? ad.y : (h == 2) ? ad.z : ad.w;
    const unsigned short* xcol = xh + (c << 2);

    float4 acc = {0.0f, 0.0f, 0.0f, 0.0f};
    float den = 0.0f;

    if (deg <= 128) {
        // ---- phase 1: weights into LDS (lane-per-edge) + denominator ----
        float4 ds = {0.0f, 0.0f, 0.0f, 0.0f};
        for (int j = base + c; j < end; j += 64) {
            int s = col[j];
            float4 as4 = *(const float4*)&a_src[s * 4];
            float l0 = as4.x + ad.x, l1 = as4.y + ad.y;
            float l2 = as4.z + ad.z, l3 = as4.w + ad.w;
            l0 = fmaxf(l0, 0.2f * l0);
            l1 = fmaxf(l1, 0.2f * l1);
            l2 = fmaxf(l2, 0.2f * l2);
            l3 = fmaxf(l3, 0.2f * l3);
            float4 wv4 = {__expf(l0), __expf(l1), __expf(l2), __expf(l3)};
            *(float4*)&wlds[wv][j - base][0] = wv4;
            ds.x += wv4.x; ds.y += wv4.y; ds.z += wv4.z; ds.w += wv4.w;
        }
        #pragma unroll
        for (int o = 32; o > 0; o >>= 1) {
            ds.x += __shfl_down(ds.x, o, 64);
            ds.y += __shfl_down(ds.y, o, 64);
            ds.z += __shfl_down(ds.z, o, 64);
            ds.w += __shfl_down(ds.w, o, 64);
        }
        float d0 = __shfl(ds.x, 0, 64);
        float d1 = __shfl(ds.y, 0, 64);
        float d2 = __shfl(ds.z, 0, 64);
        float d3 = __shfl(ds.w, 0, 64);
        den = (h == 0) ? d0 : (h == 1) ? d1 : (h == 2) ? d2 : d3;

        // ---- phase 2: gather-accumulate, weights broadcast from LDS ----
        for (int j = base; j < end; j += 4) {
            int j1 = j + 1 < e1 ? j + 1 : e1;
            int j2 = j + 2 < e1 ? j + 2 : e1;
            int j3 = j + 3 < e1 ? j + 3 : e1;
            int s0 = col[j], s1 = col[j1], s2 = col[j2], s3 = col[j3];
            float w0 = wlds[wv][j - base][h];
            float w1 = (j + 1 < end) ? wlds[wv][j1 - base][h] : 0.0f;
            float w2 = (j + 2 < end) ? wlds[wv][j2 - base][h] : 0.0f;
            float w3 = (j + 3 < end) ? wlds[wv][j3 - base][h] : 0.0f;
            u16x4 x0 = *(const u16x4*)(xcol + (size_t)s0 * 256);
            u16x4 x1 = *(const u16x4*)(xcol + (size_t)s1 * 256);
            u16x4 x2 = *(const u16x4*)(xcol + (size_t)s2 * 256);
            u16x4 x3 = *(const u16x4*)(xcol + (size_t)s3 * 256);
            acc.x += w0 * h2f(x0[0]) + w1 * h2f(x1[0]) + w2 * h2f(x2[0]) + w3 * h2f(x3[0]);
            acc.y += w0 * h2f(x0[1]) + w1 * h2f(x1[1]) + w2 * h2f(x2[1]) + w3 * h2f(x3[1]);
            acc.z += w0 * h2f(x0[2]) + w1 * h2f(x1[2]) + w2 * h2f(x2[2]) + w3 * h2f(x3[2]);
            acc.w += w0 * h2f(x0[3]) + w1 * h2f(x1[3]) + w2 * h2f(x2[3]) + w3 * h2f(x3[3]);
        }
    } else {
        // ---- slow path (deg > 128, practically never): inline weights ----
        for (int j = base; j < end; j += 4) {
            int j1 = j + 1 < e1 ? j + 1 : e1;
            int j2 = j + 2 < e1 ? j + 2 : e1;
            int j3 = j + 3 < e1 ? j + 3 : e1;
            int s0 = col[j], s1 = col[j1], s2 = col[j2], s3 = col[j3];
            float l0 = a_src[s0 * 4 + h] + adh;
            float l1 = a_src[s1 * 4 + h] + adh;
            float l2 = a_src[s2 * 4 + h] + adh;
            float l3 = a_src[s3 * 4 + h] + adh;
            l0 = fmaxf(l0, 0.2f * l0);
            l1 = fmaxf(l1, 0.2f * l1);
            l2 = fmaxf(l2, 0.2f * l2);
            l3 = fmaxf(l3, 0.2f * l3);
            float w0 = __expf(l0);
            float w1 = (j + 1 < end) ? __expf(l1) : 0.0f;
            float w2 = (j + 2 < end) ? __expf(l2) : 0.0f;
            float w3 = (j + 3 < end) ? __expf(l3) : 0.0f;
            u16x4 x0 = *(const u16x4*)(xcol + (size_t)s0 * 256);
            u16x4 x1 = *(const u16x4*)(xcol + (size_t)s1 * 256);
            u16x4 x2 = *(const u16x4*)(xcol + (size_t)s2 * 256);
            u16x4 x3 = *(const u16x4*)(xcol + (size_t)s3 * 256);
            den += (w0 + w1) + (w2 + w3);
            acc.x += w0 * h2f(x0[0]) + w1 * h2f(x1[0]) + w2 * h2f(x2[0]) + w3 * h2f(x3[0]);
            acc.y += w0 * h2f(x0[1]) + w1 * h2f(x1[1]) + w2 * h2f(x2[1]) + w3 * h2f(x3[1]);
            acc.z += w0 * h2f(x0[2]) + w1 * h2f(x1[2]) + w2 * h2f(x2[2]) + w3 * h2f(x3[2]);
            acc.w += w0 * h2f(x0[3]) + w1 * h2f(x1[3]) + w2 * h2f(x2[3]) + w3 * h2f(x3[3]);
        }
    }

    float inv = 1.0f / den;
    float4 bv = *(const float4*)(bias + (c << 2));
    float o0 = acc.x * inv + bv.x;
    float o1 = acc.y * inv + bv.y;
    float o2 = acc.z * inv + bv.z;
    float o3 = acc.w * inv + bv.w;
    o0 = (o0 > 0.0f) ? o0 : (__expf(o0) - 1.0f);
    o1 = (o1 > 0.0f) ? o1 : (__expf(o1) - 1.0f);
    o2 = (o2 > 0.0f) ? o2 : (__expf(o2) - 1.0f);
    o3 = (o3 > 0.0f) ? o3 : (__expf(o3) - 1.0f);
    if (OUTF16) {
        u16x4 H;
        H[0] = f2h(o0); H[1] = f2h(o1); H[2] = f2h(o2); H[3] = f2h(o3);
        *(u16x4*)(&outA[(size_t)n * 256 + (c << 2)]) = H;
    } else {
        u16x4 H, L;
        split_hilo16(o0, ((unsigned short*)&H)[0], ((unsigned short*)&L)[0]);
        split_hilo16(o1, ((unsigned short*)&H)[1], ((unsigned short*)&L)[1]);
        split_hilo16(o2, ((unsigned short*)&H)[2], ((unsigned short*)&L)[2]);
        split_hilo16(o3, ((unsigned short*)&H)[3], ((unsigned short*)&L)[3]);
        *(u16x4*)(&outA[(size_t)n * 256 + (c << 2)]) = H;
        *(u16x4*)(&outB[(size_t)n * 256 + (c << 2)]) = L;
    }
}

// ===========================================================================

extern "C" void kernel_launch(void* const* d_in, const int* in_sizes, int n_in,
                              void* d_out, int out_size, void* d_ws, size_t ws_size,
                              hipStream_t stream)
{
    const float* node_feats = (const float*)d_in[0];
    const float* edge_attr  = (const float*)d_in[1];
    const float* Wnp = (const float*)d_in[2];
    const float* bnp = (const float*)d_in[3];
    const float* Wep = (const float*)d_in[4];
    const float* bep = (const float*)d_in[5];
    const float* Wg1 = (const float*)d_in[6];
    const float* as1 = (const float*)d_in[7];
    const float* ad1 = (const float*)d_in[8];
    const float* bg1 = (const float*)d_in[9];
    const float* Wg2 = (const float*)d_in[10];
    const float* as2 = (const float*)d_in[11];
    const float* ad2 = (const float*)d_in[12];
    const float* bg2 = (const float*)d_in[13];
    const float* Wo  = (const float*)d_in[14];
    const float* bo  = (const float*)d_in[15];
    const int*   ei  = (const int*)d_in[16];

    const int N = in_sizes[0] / 128;   // 50000
    const int E = in_sizes[16] / 2;    // 800000
    const int* src = ei;
    const int* dst = ei + E;
    const int nchunk = (N + 255) / 256;
    const int EN = E + N;

    typedef unsigned short u16;

    // ---- workspace layout (256B-aligned regions) ----
    char* base = (char*)d_ws;
    size_t off = 0;
    auto alloc = [&](size_t bytes) -> char* {
        char* p = base + off;
        off += (bytes + 255) & ~(size_t)255;
        return p;
    };
    u16* xhh  = (u16*)alloc((size_t)N * 256 * 2);          // fp16 xh [N x 256]
    u16* x3F  = (u16*)alloc((size_t)N * 256 * 2);          // fp16 x3 [N x 256]
    u16* R3   = (u16*)alloc((size_t)N * 512 * 2);          // x4H/x4L (fp16 hilo)
    u16* nefF = (u16*)alloc((size_t)N * 32 * 2);           // compact nef fp16
    float* a_src = (float*)alloc((size_t)N * 4 * 4);
    float* a_dst = (float*)alloc((size_t)N * 4 * 4);
    float* Wc    = (float*)alloc(144 * 256 * 4);           // composed front weights
    float* c1    = (float*)alloc(256 * 4);                 // composed front bias
    u16* PcH  = (u16*)alloc(160 * 256 * 2);
    u16* PcL  = (u16*)alloc(160 * 256 * 2);
    u16* Pg2H = (u16*)alloc(256 * 256 * 2);
    u16* Pg2L = (u16*)alloc(256 * 256 * 2);
    u16* PoH  = (u16*)alloc(256 * 256 * 2);
    u16* PoL  = (u16*)alloc(256 * 256 * 2);
    int* cnt       = (int*)alloc((size_t)N * 4);
    int* rowptr    = (int*)alloc((size_t)(N + 1) * 4);
    int* fillptr   = (int*)alloc((size_t)N * 4);
    int* chunk_sum = (int*)alloc((size_t)nchunk * 4);
    int* chunk_off = (int*)alloc((size_t)nchunk * 4);
    int* colv      = (int*)alloc((size_t)EN * 4);
    int* eid       = (int*)alloc((size_t)EN * 4);

    u16* x4H = R3;
    u16* x4L = R3 + (size_t)N * 256;

    float* out = (float*)d_out;
    dim3 ggrid((N + 63) / 64, 2);

    // ---- CSR build ----
    hipMemsetAsync(cnt, 0, (size_t)N * sizeof(int), stream);
    count_kernel<<<(E + 255) / 256, 256, 0, stream>>>(dst, cnt, E);
    scan1_kernel<<<nchunk, 256, 0, stream>>>(cnt, chunk_sum, N);
    scan2_kernel<<<1, 256, 0, stream>>>(chunk_sum, chunk_off, nchunk);
    scan3_kernel<<<nchunk, 256, 0, stream>>>(cnt, chunk_off, rowptr, fillptr, colv, eid, N);
    fill_kernel<<<(E + 255) / 256, 256, 0, stream>>>(src, dst, fillptr, colv, eid, E);

    // ---- nef (compact fp16); weight compose + packing ----
    nef_csr_kernel<<<(N + 3) / 4, 256, 0, stream>>>(edge_attr, rowptr, eid, nefF, N);
    compose_w1_kernel<<<145, 256, 0, stream>>>(Wnp, Wep, bnp, bep, Wg1, Wc, c1);
    {
        const int total = 160 * 256 + 256 * 256 + 256 * 256;
        pack3_w_kernel<<<(total + 255) / 256, 256, 0, stream>>>(
            Wc, PcH, PcL, Wg2, Pg2H, Pg2L, Wo, PoH, PoL);
    }

    // ---- GAT layer 1: composed GEMM (K=160; f32 nf direct + nef) -> agg ----
    mfma_gemm_kernel<5, 3, 2, true><<<ggrid, 256, 0, stream>>>(
        nefF, nullptr, node_feats, 160, PcH, PcL, c1, nullptr, xhh, nullptr,
        256, 0, N, as1, ad1, a_src, a_dst);
    gat_agg_csr_kernel<true><<<(N + 3) / 4, 256, 0, stream>>>(
        xhh, rowptr, colv, a_src, a_dst, bg1, x3F, nullptr, N);

    // ---- GAT layer 2 (fp16 A single, all-preload) ----
    mfma_gemm_kernel<8, 1, 2, true><<<ggrid, 256, 0, stream>>>(
        x3F, nullptr, nullptr, 256, Pg2H, Pg2L, nullptr, nullptr, xhh, nullptr,
        256, 0, N, as2, ad2, a_src, a_dst);
    gat_agg_csr_kernel<false><<<(N + 3) / 4, 256, 0, stream>>>(
        xhh, rowptr, colv, a_src, a_dst, bg2, x4H, x4L, N);

    // ---- out = x4 @ Wo + bo -> d_out (f32), fp16 hilo A, all-preload ----
    mfma_gemm_kernel<8, 0, 0, false><<<ggrid, 256, 0, stream>>>(
        x4H, x4L, nullptr, 256, PoH, PoL, bo, out, nullptr, nullptr,
        256, 0, N, nullptr, nullptr, nullptr, nullptr);
}